// Round 1
// baseline (416.255 us; speedup 1.0000x reference)
//
#include <hip/hip_runtime.h>
#include <hip/hip_bf16.h>

// NonLocal block == flash attention (4 heads, N=4096, D=128) + 1x1-conv GEMMs.
// All matmuls via v_mfma_f32_16x16x32_bf16, fp32 accumulate.

typedef float f32x4 __attribute__((ext_vector_type(4)));
typedef short s16x8 __attribute__((ext_vector_type(8)));

#define B_  4
#define C_  256
#define CI_ 128
#define N_  4096

// workspace layout (bytes); total ~24.3 MB
#define OFF_XT   0ull                    // bf16 [B][N][C]   8 MB   x transposed
#define OFF_Q    (8ull  << 20)           // bf16 [B][N][CI]  4 MB   theta^T (scaled)
#define OFF_K    (12ull << 20)           // bf16 [B][N][CI]  4 MB   phi^T
#define OFF_G    (16ull << 20)           // bf16 [B][CI][N]  4 MB   g (natural layout = V^T)
#define OFF_O    (20ull << 20)           // bf16 [B][N][CI]  4 MB   attention output
#define OFF_WQK  (24ull << 20)           // bf16 [256][256]  (rows 0-127 theta*rs, 128-255 phi)
#define OFF_WG   (OFF_WQK + 131072)      // bf16 [128][256]
#define OFF_WOUT (OFF_WG  + 65536)       // bf16 [256][128]
#define OFF_BQK  (OFF_WOUT + 65536)      // f32 [256]
#define OFF_BG   (OFF_BQK + 1024)        // f32 [128]
#define OFF_BOUT (OFF_BG  + 512)         // f32 [256]

__device__ inline f32x4 mfma16(s16x8 a, s16x8 b, f32x4 c) {
    return __builtin_amdgcn_mfma_f32_16x16x32_bf16(a, b, c, 0, 0, 0);
}
__device__ inline s16x8 ld8(const __hip_bfloat16* p) { return *(const s16x8*)p; }

// ---------------- weight prep: fp32 -> bf16, fold 1/sqrt(Ci) into theta ----
__global__ void prep_weights(const float* wg, const float* bg,
                             const float* wt, const float* bt,
                             const float* wp, const float* bp,
                             const float* wo, const float* bo, char* ws) {
    __hip_bfloat16* Wqk  = (__hip_bfloat16*)(ws + OFF_WQK);
    __hip_bfloat16* Wg   = (__hip_bfloat16*)(ws + OFF_WG);
    __hip_bfloat16* Wout = (__hip_bfloat16*)(ws + OFF_WOUT);
    float* Bqk  = (float*)(ws + OFF_BQK);
    float* Bg   = (float*)(ws + OFF_BG);
    float* Bout = (float*)(ws + OFF_BOUT);
    const float rs = 0.08838834764831845f;  // 1/sqrt(128)
    int idx = blockIdx.x * 256 + threadIdx.x;
    if (idx < 65536) {
        int r = idx >> 8, c = idx & 255;
        float v = (r < 128) ? wt[r * 256 + c] * rs : wp[(r - 128) * 256 + c];
        Wqk[idx] = __float2bfloat16(v);
    }
    if (idx < 32768) {
        Wg[idx]   = __float2bfloat16(wg[idx]);
        Wout[idx] = __float2bfloat16(wo[idx]);
    }
    if (idx < 256) { Bqk[idx] = (idx < 128) ? bt[idx] * rs : bp[idx - 128]; Bout[idx] = bo[idx]; }
    if (idx < 128) Bg[idx] = bg[idx];
}

// ---------------- x [B][C][N] f32 -> XT [B][N][C] bf16 (LDS tiled) ---------
__global__ __launch_bounds__(256) void transpose_x(const float* x, char* ws) {
    __shared__ float tile[32][33];
    __hip_bfloat16* XT = (__hip_bfloat16*)(ws + OFF_XT);
    int b = blockIdx.z;
    int n0 = blockIdx.x * 32, c0 = blockIdx.y * 32;
    int tx = threadIdx.x & 31, ty = threadIdx.x >> 5;  // ty 0..7
#pragma unroll
    for (int r = 0; r < 4; r++)
        tile[ty + 8 * r][tx] = x[(size_t)(b * C_ + c0 + ty + 8 * r) * N_ + n0 + tx];
    __syncthreads();
#pragma unroll
    for (int r = 0; r < 4; r++)
        XT[(size_t)(b * N_ + n0 + ty + 8 * r) * C_ + c0 + tx] =
            __float2bfloat16(tile[tx][ty + 8 * r]);
}

// ---------------- Q/K projection: D[n,o] = sum_c XT[n,c]*Wqk[o,c] + bias ---
// grid (64,4,4), block 256 (4 waves); wave = 16 n-rows x 64 o-cols
__global__ __launch_bounds__(256) void gemm_qk(char* ws) {
    const __hip_bfloat16* XT = (const __hip_bfloat16*)(ws + OFF_XT);
    const __hip_bfloat16* W  = (const __hip_bfloat16*)(ws + OFF_WQK);
    const float* Bias = (const float*)(ws + OFF_BQK);
    __hip_bfloat16* Q  = (__hip_bfloat16*)(ws + OFF_Q);
    __hip_bfloat16* Kb = (__hip_bfloat16*)(ws + OFF_K);
    int b = blockIdx.z;
    int w = threadIdx.x >> 6, l = threadIdx.x & 63, lr = l & 15, lg = l >> 4;
    int n0 = blockIdx.x * 64 + w * 16;
    int o0 = blockIdx.y * 64;
    f32x4 acc[4] = {};
    const __hip_bfloat16* Arow = XT + (size_t)(b * N_ + n0 + lr) * C_ + lg * 8;
#pragma unroll
    for (int kk = 0; kk < 8; kk++) {
        s16x8 a = ld8(Arow + kk * 32);
#pragma unroll
        for (int f = 0; f < 4; f++) {
            s16x8 bb = ld8(W + (size_t)(o0 + 16 * f + lr) * C_ + kk * 32 + lg * 8);
            acc[f] = mfma16(a, bb, acc[f]);
        }
    }
#pragma unroll
    for (int f = 0; f < 4; f++) {
        int o = o0 + 16 * f + lr;
        float bias = Bias[o];
#pragma unroll
        for (int i = 0; i < 4; i++) {
            int n = n0 + lg * 4 + i;
            float v = acc[f][i] + bias;
            if (o < 128) Q [(size_t)(b * N_ + n) * CI_ + o]         = __float2bfloat16(v);
            else         Kb[(size_t)(b * N_ + n) * CI_ + (o - 128)] = __float2bfloat16(v);
        }
    }
}

// ---------------- g projection: D[o,n] = sum_c Wg[o,c]*XT[n,c] + bias ------
// grid (64,2,4), block 256; wave = 16 o-rows x 64 n-cols; out G[b][o][n]
__global__ __launch_bounds__(256) void gemm_g(char* ws) {
    const __hip_bfloat16* XT = (const __hip_bfloat16*)(ws + OFF_XT);
    const __hip_bfloat16* Wg = (const __hip_bfloat16*)(ws + OFF_WG);
    const float* Bg = (const float*)(ws + OFF_BG);
    __hip_bfloat16* G = (__hip_bfloat16*)(ws + OFF_G);
    int b = blockIdx.z;
    int w = threadIdx.x >> 6, l = threadIdx.x & 63, lr = l & 15, lg = l >> 4;
    int o0 = blockIdx.y * 64 + w * 16;
    int n0 = blockIdx.x * 64;
    f32x4 acc[4] = {};
#pragma unroll
    for (int kk = 0; kk < 8; kk++) {
        s16x8 a = ld8(Wg + (size_t)(o0 + lr) * C_ + kk * 32 + lg * 8);
#pragma unroll
        for (int f = 0; f < 4; f++) {
            s16x8 bb = ld8(XT + (size_t)(b * N_ + n0 + 16 * f + lr) * C_ + kk * 32 + lg * 8);
            acc[f] = mfma16(a, bb, acc[f]);
        }
    }
#pragma unroll
    for (int f = 0; f < 4; f++) {
#pragma unroll
        for (int i = 0; i < 4; i++) {
            int o = o0 + lg * 4 + i;
            int n = n0 + 16 * f + lr;
            G[(size_t)(b * CI_ + o) * N_ + n] = __float2bfloat16(acc[f][i] + Bg[o]);
        }
    }
}

// ---------------- flash attention: O[n,c] = softmax(Q K^T) V ---------------
// grid (128,4), block 128 (2 waves); wave = 16 q-rows, KVBLK=32
__global__ __launch_bounds__(128) void flash(char* ws) {
    const __hip_bfloat16* Q  = (const __hip_bfloat16*)(ws + OFF_Q);
    const __hip_bfloat16* Kb = (const __hip_bfloat16*)(ws + OFF_K);
    const __hip_bfloat16* G  = (const __hip_bfloat16*)(ws + OFF_G);
    __hip_bfloat16* O = (__hip_bfloat16*)(ws + OFF_O);
    __shared__ __hip_bfloat16 pbuf[2][16][48];  // row stride 96B (16B-aligned b128 reads)
    int b = blockIdx.y;
    int w = threadIdx.x >> 6, l = threadIdx.x & 63, lr = l & 15, lg = l >> 4;
    int q0 = blockIdx.x * 32 + w * 16;

    s16x8 qa[4];
    const __hip_bfloat16* qrow = Q + (size_t)(b * N_ + q0 + lr) * CI_ + lg * 8;
#pragma unroll
    for (int kk = 0; kk < 4; kk++) qa[kk] = ld8(qrow + kk * 32);

    f32x4 oacc[8] = {};
    float m_i[4] = {-1e30f, -1e30f, -1e30f, -1e30f};
    float l_i[4] = {0.f, 0.f, 0.f, 0.f};

    for (int j0 = 0; j0 < N_; j0 += 32) {
        f32x4 s[2] = {};
#pragma unroll
        for (int kk = 0; kk < 4; kk++) {
#pragma unroll
            for (int f = 0; f < 2; f++) {
                s16x8 kb = ld8(Kb + (size_t)(b * N_ + j0 + 16 * f + lr) * CI_ + kk * 32 + lg * 8);
                s[f] = mfma16(qa[kk], kb, s[f]);
            }
        }
        float alpha[4], p0[4], p1[4];
#pragma unroll
        for (int i = 0; i < 4; i++) {
            float t = fmaxf(s[0][i], s[1][i]);
            t = fmaxf(t, __shfl_xor(t, 1));
            t = fmaxf(t, __shfl_xor(t, 2));
            t = fmaxf(t, __shfl_xor(t, 4));
            t = fmaxf(t, __shfl_xor(t, 8));
            float mn = fmaxf(m_i[i], t);
            alpha[i] = __expf(m_i[i] - mn);
            m_i[i] = mn;
            p0[i] = __expf(s[0][i] - mn);
            p1[i] = __expf(s[1][i] - mn);
            float rs_ = p0[i] + p1[i];
            rs_ += __shfl_xor(rs_, 1);
            rs_ += __shfl_xor(rs_, 2);
            rs_ += __shfl_xor(rs_, 4);
            rs_ += __shfl_xor(rs_, 8);
            l_i[i] = l_i[i] * alpha[i] + rs_;
        }
#pragma unroll
        for (int cf = 0; cf < 8; cf++)
#pragma unroll
            for (int i = 0; i < 4; i++) oacc[cf][i] *= alpha[i];
        // P (D-layout) -> LDS -> A-layout fragment
#pragma unroll
        for (int i = 0; i < 4; i++) {
            pbuf[w][lg * 4 + i][lr]      = __float2bfloat16(p0[i]);
            pbuf[w][lg * 4 + i][16 + lr] = __float2bfloat16(p1[i]);
        }
        s16x8 pa = *(const s16x8*)(&pbuf[w][lr][lg * 8]);
#pragma unroll
        for (int cf = 0; cf < 8; cf++) {
            s16x8 vb = ld8(G + (size_t)(b * CI_ + 16 * cf + lr) * N_ + j0 + lg * 8);
            oacc[cf] = mfma16(pa, vb, oacc[cf]);
        }
    }
#pragma unroll
    for (int i = 0; i < 4; i++) {
        float inv = 1.0f / l_i[i];
        int n = q0 + lg * 4 + i;
#pragma unroll
        for (int cf = 0; cf < 8; cf++)
            O[(size_t)(b * N_ + n) * CI_ + 16 * cf + lr] = __float2bfloat16(oacc[cf][i] * inv);
    }
}

// ---------------- out projection + bias + residual, fp32 out ---------------
// grid (64,4,4), block 256; wave = 16 o-rows x 64 n-cols
__global__ __launch_bounds__(256) void gemm_out(const float* x, char* ws, float* y) {
    const __hip_bfloat16* Ob = (const __hip_bfloat16*)(ws + OFF_O);
    const __hip_bfloat16* Wo = (const __hip_bfloat16*)(ws + OFF_WOUT);
    const float* Bout = (const float*)(ws + OFF_BOUT);
    int b = blockIdx.z;
    int w = threadIdx.x >> 6, l = threadIdx.x & 63, lr = l & 15, lg = l >> 4;
    int o0 = blockIdx.y * 64 + w * 16;
    int n0 = blockIdx.x * 64;
    f32x4 acc[4] = {};
#pragma unroll
    for (int kk = 0; kk < 4; kk++) {
        s16x8 a = ld8(Wo + (size_t)(o0 + lr) * CI_ + kk * 32 + lg * 8);
#pragma unroll
        for (int f = 0; f < 4; f++) {
            s16x8 bb = ld8(Ob + (size_t)(b * N_ + n0 + 16 * f + lr) * CI_ + kk * 32 + lg * 8);
            acc[f] = mfma16(a, bb, acc[f]);
        }
    }
#pragma unroll
    for (int f = 0; f < 4; f++) {
#pragma unroll
        for (int i = 0; i < 4; i++) {
            int o = o0 + lg * 4 + i;
            int n = n0 + 16 * f + lr;
            size_t idx = (size_t)(b * C_ + o) * N_ + n;
            y[idx] = acc[f][i] + Bout[o] + x[idx];
        }
    }
}

extern "C" void kernel_launch(void* const* d_in, const int* in_sizes, int n_in,
                              void* d_out, int out_size, void* d_ws, size_t ws_size,
                              hipStream_t stream) {
    const float* x  = (const float*)d_in[0];
    const float* wg = (const float*)d_in[1];
    const float* bg = (const float*)d_in[2];
    const float* wt = (const float*)d_in[3];
    const float* bt = (const float*)d_in[4];
    const float* wp = (const float*)d_in[5];
    const float* bp = (const float*)d_in[6];
    const float* wo = (const float*)d_in[7];
    const float* bo = (const float*)d_in[8];
    char* ws = (char*)d_ws;
    float* y = (float*)d_out;

    prep_weights<<<256, 256, 0, stream>>>(wg, bg, wt, bt, wp, bp, wo, bo, ws);
    transpose_x<<<dim3(128, 8, 4), 256, 0, stream>>>(x, ws);
    gemm_qk<<<dim3(64, 4, 4), 256, 0, stream>>>(ws);
    gemm_g<<<dim3(64, 2, 4), 256, 0, stream>>>(ws);
    flash<<<dim3(128, 4), 128, 0, stream>>>(ws);
    gemm_out<<<dim3(64, 4, 4), 256, 0, stream>>>(x, ws, y);
}

// Round 2
// 213.590 us; speedup vs baseline: 1.9488x; 1.9488x over previous
//
#include <hip/hip_runtime.h>
#include <hip/hip_bf16.h>

// NonLocal block == flash attention (4 heads, N=4096, D=128) + 1x1-conv GEMMs.
// Round 2: swapped QK^T (in-register softmax), 32 q/wave, split-KV, exp2.

typedef float f32x4 __attribute__((ext_vector_type(4)));
typedef short s16x8 __attribute__((ext_vector_type(8)));

#define B_  4
#define C_  256
#define CI_ 128
#define N_  4096

// workspace layout (bytes)
#define OFF_XT   0ull                    // bf16 [B][N][C]   8 MB (dead after gemms; reused for partials if ws small)
#define OFF_Q    (8ull  << 20)           // bf16 [B][N][CI]  4 MB   theta^T (scaled by log2e/sqrt(Ci))
#define OFF_K    (12ull << 20)           // bf16 [B][N][CI]  4 MB   phi^T
#define OFF_G    (16ull << 20)           // bf16 [B][CI][N]  4 MB   g (V^T layout)
#define OFF_O    (20ull << 20)           // bf16 [B][N][CI]  4 MB   attention output (combined)
#define OFF_WQK  (24ull << 20)
#define OFF_WG   (OFF_WQK + 131072)
#define OFF_WOUT (OFF_WG  + 65536)
#define OFF_BQK  (OFF_WOUT + 65536)
#define OFF_BG   (OFF_BQK + 1024)
#define OFF_BOUT (OFF_BG  + 512)
#define OFF_END  (OFF_BOUT + 1024)       // = 25430528

__device__ inline f32x4 mfma16(s16x8 a, s16x8 b, f32x4 c) {
    return __builtin_amdgcn_mfma_f32_16x16x32_bf16(a, b, c, 0, 0, 0);
}
__device__ inline s16x8 ld8(const __hip_bfloat16* p) { return *(const s16x8*)p; }
__device__ inline float b2f(short u) {
    return __uint_as_float(((unsigned int)(unsigned short)u) << 16);
}
__device__ inline unsigned int pk2(float a, float b) {
    __hip_bfloat162 h;
    h.x = __float2bfloat16(a); h.y = __float2bfloat16(b);
    return *(unsigned int*)&h;
}

// ---------------- weight prep: fp32 -> bf16; fold log2e/sqrt(Ci) into theta
__global__ void prep_weights(const float* wg, const float* bg,
                             const float* wt, const float* bt,
                             const float* wp, const float* bp,
                             const float* wo, const float* bo, char* ws) {
    __hip_bfloat16* Wqk  = (__hip_bfloat16*)(ws + OFF_WQK);
    __hip_bfloat16* Wg   = (__hip_bfloat16*)(ws + OFF_WG);
    __hip_bfloat16* Wout = (__hip_bfloat16*)(ws + OFF_WOUT);
    float* Bqk  = (float*)(ws + OFF_BQK);
    float* Bg   = (float*)(ws + OFF_BG);
    float* Bout = (float*)(ws + OFF_BOUT);
    // 1/sqrt(128) * log2(e): softmax computed in base-2 throughout
    const float rs = 0.08838834764831845f * 1.4426950408889634f;
    int idx = blockIdx.x * 256 + threadIdx.x;
    if (idx < 65536) {
        int r = idx >> 8, c = idx & 255;
        float v = (r < 128) ? wt[r * 256 + c] * rs : wp[(r - 128) * 256 + c];
        Wqk[idx] = __float2bfloat16(v);
    }
    if (idx < 32768) {
        Wg[idx]   = __float2bfloat16(wg[idx]);
        Wout[idx] = __float2bfloat16(wo[idx]);
    }
    if (idx < 256) { Bqk[idx] = (idx < 128) ? bt[idx] * rs : bp[idx - 128]; Bout[idx] = bo[idx]; }
    if (idx < 128) Bg[idx] = bg[idx];
}

// ---------------- x [B][C][N] f32 -> XT [B][N][C] bf16 -------------------
__global__ __launch_bounds__(256) void transpose_x(const float* x, char* ws) {
    __shared__ float tile[32][33];
    __hip_bfloat16* XT = (__hip_bfloat16*)(ws + OFF_XT);
    int b = blockIdx.z;
    int n0 = blockIdx.x * 32, c0 = blockIdx.y * 32;
    int tx = threadIdx.x & 31, ty = threadIdx.x >> 5;
#pragma unroll
    for (int r = 0; r < 4; r++)
        tile[ty + 8 * r][tx] = x[(size_t)(b * C_ + c0 + ty + 8 * r) * N_ + n0 + tx];
    __syncthreads();
#pragma unroll
    for (int r = 0; r < 4; r++)
        XT[(size_t)(b * N_ + n0 + ty + 8 * r) * C_ + c0 + tx] =
            __float2bfloat16(tile[tx][ty + 8 * r]);
}

// ---------------- Q/K projection ------------------------------------------
__global__ __launch_bounds__(256) void gemm_qk(char* ws) {
    const __hip_bfloat16* XT = (const __hip_bfloat16*)(ws + OFF_XT);
    const __hip_bfloat16* W  = (const __hip_bfloat16*)(ws + OFF_WQK);
    const float* Bias = (const float*)(ws + OFF_BQK);
    __hip_bfloat16* Q  = (__hip_bfloat16*)(ws + OFF_Q);
    __hip_bfloat16* Kb = (__hip_bfloat16*)(ws + OFF_K);
    int b = blockIdx.z;
    int w = threadIdx.x >> 6, l = threadIdx.x & 63, lr = l & 15, lg = l >> 4;
    int n0 = blockIdx.x * 64 + w * 16;
    int o0 = blockIdx.y * 64;
    f32x4 acc[4] = {};
    const __hip_bfloat16* Arow = XT + (size_t)(b * N_ + n0 + lr) * C_ + lg * 8;
#pragma unroll
    for (int kk = 0; kk < 8; kk++) {
        s16x8 a = ld8(Arow + kk * 32);
#pragma unroll
        for (int f = 0; f < 4; f++) {
            s16x8 bb = ld8(W + (size_t)(o0 + 16 * f + lr) * C_ + kk * 32 + lg * 8);
            acc[f] = mfma16(a, bb, acc[f]);
        }
    }
#pragma unroll
    for (int f = 0; f < 4; f++) {
        int o = o0 + 16 * f + lr;
        float bias = Bias[o];
#pragma unroll
        for (int i = 0; i < 4; i++) {
            int n = n0 + lg * 4 + i;
            float v = acc[f][i] + bias;
            if (o < 128) Q [(size_t)(b * N_ + n) * CI_ + o]         = __float2bfloat16(v);
            else         Kb[(size_t)(b * N_ + n) * CI_ + (o - 128)] = __float2bfloat16(v);
        }
    }
}

// ---------------- g projection --------------------------------------------
__global__ __launch_bounds__(256) void gemm_g(char* ws) {
    const __hip_bfloat16* XT = (const __hip_bfloat16*)(ws + OFF_XT);
    const __hip_bfloat16* Wg = (const __hip_bfloat16*)(ws + OFF_WG);
    const float* Bg = (const float*)(ws + OFF_BG);
    __hip_bfloat16* G = (__hip_bfloat16*)(ws + OFF_G);
    int b = blockIdx.z;
    int w = threadIdx.x >> 6, l = threadIdx.x & 63, lr = l & 15, lg = l >> 4;
    int o0 = blockIdx.y * 64 + w * 16;
    int n0 = blockIdx.x * 64;
    f32x4 acc[4] = {};
#pragma unroll
    for (int kk = 0; kk < 8; kk++) {
        s16x8 a = ld8(Wg + (size_t)(o0 + lr) * C_ + kk * 32 + lg * 8);
#pragma unroll
        for (int f = 0; f < 4; f++) {
            s16x8 bb = ld8(XT + (size_t)(b * N_ + n0 + 16 * f + lr) * C_ + kk * 32 + lg * 8);
            acc[f] = mfma16(a, bb, acc[f]);
        }
    }
#pragma unroll
    for (int f = 0; f < 4; f++) {
#pragma unroll
        for (int i = 0; i < 4; i++) {
            int o = o0 + lg * 4 + i;
            int n = n0 + 16 * f + lr;
            G[(size_t)(b * CI_ + o) * N_ + n] = __float2bfloat16(acc[f][i] + Bg[o]);
        }
    }
}

// ---------------- flash v2: swapped QK^T, 32 q/wave, split-KV --------------
// grid: nchunk*64 blocks of 256 (4 waves). Block linear id L:
//   nchunk==4: pair=L&15 (b=pair>>2, cz=pair&3), qt=L>>4  -> XCD L2 locality
//   nchunk==2: pair=L&7  (b=pair>>1, cz=pair&1), qt=L>>3
// wave handles 32 q rows; KVBLK=64; partial O (unnormalized bf16) + (m,l).
__global__ __launch_bounds__(256) void flash2(char* ws, int nchunk,
                                              unsigned long long off_part,
                                              unsigned long long off_ml) {
    const __hip_bfloat16* Q  = (const __hip_bfloat16*)(ws + OFF_Q);
    const __hip_bfloat16* Kb = (const __hip_bfloat16*)(ws + OFF_K);
    const __hip_bfloat16* G  = (const __hip_bfloat16*)(ws + OFF_G);
    __hip_bfloat16* OP = (__hip_bfloat16*)(ws + off_part);
    float* ML = (float*)(ws + off_ml);

    __shared__ char pbuf[4][2][2048];   // [wave][qf][16 rows x 128 B], XOR-swizzled

    int L = blockIdx.x;
    int pair, qt, b, cz;
    if (nchunk == 4) { pair = L & 15; qt = L >> 4; b = pair >> 2; cz = pair & 3; }
    else             { pair = L & 7;  qt = L >> 3; b = pair >> 1; cz = pair & 1; }
    int CH = N_ / nchunk;
    int jb = cz * CH, je = jb + CH;

    int w = threadIdx.x >> 6, l = threadIdx.x & 63, lr = l & 15, lg = l >> 4;
    int q0 = qt * 128 + w * 32;
    int swz = (lr & 7) << 4;
    char* pw = &pbuf[w][0][0];

    // Q as B-operand: lane holds Q[k = kk*32+lg*8+i][col q = q0+16qf+lr]
    s16x8 qa[2][4];
#pragma unroll
    for (int qf = 0; qf < 2; qf++) {
        const __hip_bfloat16* qrow = Q + ((size_t)b * N_ + q0 + 16 * qf + lr) * CI_ + lg * 8;
#pragma unroll
        for (int kk = 0; kk < 4; kk++) qa[qf][kk] = ld8(qrow + kk * 32);
    }

    f32x4 oacc[2][8] = {};
    float m_i[2] = {-1e30f, -1e30f}, l_i[2] = {0.f, 0.f};

    for (int j0 = jb; j0 < je; j0 += 64) {
        // S^T = K Q : D[col=q(lr)][row=j(lg*4+i)] per 16-j tile t
        f32x4 s[2][4] = {};
#pragma unroll
        for (int t = 0; t < 4; t++) {
            const __hip_bfloat16* krow =
                Kb + ((size_t)b * N_ + j0 + 16 * t + lr) * CI_ + lg * 8;
#pragma unroll
            for (int kk = 0; kk < 4; kk++) {
                s16x8 kf = ld8(krow + kk * 32);
                s[0][t] = mfma16(kf, qa[0][kk], s[0][t]);
                s[1][t] = mfma16(kf, qa[1][kk], s[1][t]);
            }
        }
        // in-register softmax (base 2); lane owns 16 j-values of one q
        float al[2];
#pragma unroll
        for (int qf = 0; qf < 2; qf++) {
            f32x4 m4 = s[qf][0];
#pragma unroll
            for (int t = 1; t < 4; t++) {
                m4[0] = fmaxf(m4[0], s[qf][t][0]); m4[1] = fmaxf(m4[1], s[qf][t][1]);
                m4[2] = fmaxf(m4[2], s[qf][t][2]); m4[3] = fmaxf(m4[3], s[qf][t][3]);
            }
            float tm = fmaxf(fmaxf(m4[0], m4[1]), fmaxf(m4[2], m4[3]));
            tm = fmaxf(tm, __shfl_xor(tm, 16));
            tm = fmaxf(tm, __shfl_xor(tm, 32));
            float mn = fmaxf(m_i[qf], tm);
            al[qf] = exp2f(m_i[qf] - mn);
            m_i[qf] = mn;
            f32x4 sum4 = {};
#pragma unroll
            for (int t = 0; t < 4; t++) {
#pragma unroll
                for (int i = 0; i < 4; i++) s[qf][t][i] = exp2f(s[qf][t][i] - mn);
                sum4 += s[qf][t];
            }
            float rs = (sum4[0] + sum4[1]) + (sum4[2] + sum4[3]);
            rs += __shfl_xor(rs, 16);
            rs += __shfl_xor(rs, 32);
            l_i[qf] = l_i[qf] * al[qf] + rs;
            // pack P -> LDS (XOR-swizzled rows; row = q = lr)
            char* base = pw + qf * 2048 + lr * 128;
#pragma unroll
            for (int t = 0; t < 4; t++) {
                unsigned int lo = pk2(s[qf][t][0], s[qf][t][1]);
                unsigned int hi = pk2(s[qf][t][2], s[qf][t][3]);
                int byte0 = (32 * t + 8 * lg) ^ swz;
                *(unsigned int*)(base + byte0)     = lo;
                *(unsigned int*)(base + byte0 + 4) = hi;
            }
        }
        // rescale O by per-row alpha (row q = lg*4+i in D-layout)
#pragma unroll
        for (int qf = 0; qf < 2; qf++) {
            f32x4 a4;
#pragma unroll
            for (int i = 0; i < 4; i++) a4[i] = __shfl(al[qf], lg * 4 + i);
#pragma unroll
            for (int cf = 0; cf < 8; cf++) oacc[qf][cf] *= a4;
        }
        // P fragments back (A-operand: row q = lr, k = j = 32u+lg*8+i)
        s16x8 pa[2][2];
#pragma unroll
        for (int qf = 0; qf < 2; qf++)
#pragma unroll
            for (int u = 0; u < 2; u++)
                pa[qf][u] = *(const s16x8*)(pw + qf * 2048 + lr * 128 +
                                            ((64 * u + 16 * lg) ^ swz));
        // PV: V from G (V^T layout), shared across both q-fragments
#pragma unroll
        for (int u = 0; u < 2; u++) {
#pragma unroll
            for (int cf = 0; cf < 8; cf++) {
                s16x8 vb = ld8(G + ((size_t)b * CI_ + 16 * cf + lr) * N_ +
                               j0 + 32 * u + lg * 8);
                oacc[0][cf] = mfma16(pa[0][u], vb, oacc[0][cf]);
                oacc[1][cf] = mfma16(pa[1][u], vb, oacc[1][cf]);
            }
        }
    }
    // write unnormalized partial O + (m,l)
#pragma unroll
    for (int qf = 0; qf < 2; qf++) {
#pragma unroll
        for (int i = 0; i < 4; i++) {
            size_t row = ((size_t)(cz * B_ + b) * N_ + q0 + 16 * qf + lg * 4 + i) * CI_;
#pragma unroll
            for (int cf = 0; cf < 8; cf++)
                OP[row + 16 * cf + lr] = __float2bfloat16(oacc[qf][cf][i]);
        }
        if (lg == 0) {
            size_t mi = ((size_t)(cz * B_ + b) * N_ + q0 + 16 * qf + lr) * 2;
            ML[mi] = m_i[qf];
            ML[mi + 1] = l_i[qf];
        }
    }
}

// ---------------- combine split-KV partials -> O ---------------------------
template <int NC>
__global__ __launch_bounds__(256) void combine(char* ws,
                                               unsigned long long off_part,
                                               unsigned long long off_ml) {
    const __hip_bfloat16* OP = (const __hip_bfloat16*)(ws + off_part);
    const float* ML = (const float*)(ws + off_ml);
    __hip_bfloat16* O = (__hip_bfloat16*)(ws + OFF_O);
    int idx = blockIdx.x * 256 + threadIdx.x;      // B*N*16 threads
    int cg = idx & 15, n = (idx >> 4) & (N_ - 1), b = idx >> 16;
    float mz[NC], lz[NC], M = -1e30f;
#pragma unroll
    for (int z = 0; z < NC; z++) {
        size_t mi = ((size_t)(z * B_ + b) * N_ + n) * 2;
        mz[z] = ML[mi]; lz[z] = ML[mi + 1];
        M = fmaxf(M, mz[z]);
    }
    float Lsum = 0.f, wz[NC];
#pragma unroll
    for (int z = 0; z < NC; z++) { wz[z] = exp2f(mz[z] - M); Lsum += lz[z] * wz[z]; }
    float inv = 1.f / Lsum;
    float o[8] = {};
#pragma unroll
    for (int z = 0; z < NC; z++) {
        s16x8 v = ld8(OP + ((size_t)(z * B_ + b) * N_ + n) * CI_ + cg * 8);
#pragma unroll
        for (int i = 0; i < 8; i++) o[i] += wz[z] * b2f(v[i]);
    }
    s16x8 r;
#pragma unroll
    for (int i = 0; i < 8; i++) {
        __hip_bfloat16 h = __float2bfloat16(o[i] * inv);
        r[i] = *(short*)&h;
    }
    *(s16x8*)(O + ((size_t)b * N_ + n) * CI_ + cg * 8) = r;
}

// ---------------- out projection + bias + residual -------------------------
__global__ __launch_bounds__(256) void gemm_out(const float* x, char* ws, float* y) {
    const __hip_bfloat16* Ob = (const __hip_bfloat16*)(ws + OFF_O);
    const __hip_bfloat16* Wo = (const __hip_bfloat16*)(ws + OFF_WOUT);
    const float* Bout = (const float*)(ws + OFF_BOUT);
    int b = blockIdx.z;
    int w = threadIdx.x >> 6, l = threadIdx.x & 63, lr = l & 15, lg = l >> 4;
    int o0 = blockIdx.y * 64 + w * 16;
    int n0 = blockIdx.x * 64;
    f32x4 acc[4] = {};
#pragma unroll
    for (int kk = 0; kk < 4; kk++) {
        s16x8 a = ld8(Wo + (size_t)(o0 + lr) * CI_ + kk * 32 + lg * 8);
#pragma unroll
        for (int f = 0; f < 4; f++) {
            s16x8 bb = ld8(Ob + (size_t)(b * N_ + n0 + 16 * f + lr) * CI_ + kk * 32 + lg * 8);
            acc[f] = mfma16(a, bb, acc[f]);
        }
    }
#pragma unroll
    for (int f = 0; f < 4; f++) {
#pragma unroll
        for (int i = 0; i < 4; i++) {
            int o = o0 + lg * 4 + i;
            int n = n0 + 16 * f + lr;
            size_t idx = (size_t)(b * C_ + o) * N_ + n;
            y[idx] = acc[f][i] + Bout[o] + x[idx];
        }
    }
}

extern "C" void kernel_launch(void* const* d_in, const int* in_sizes, int n_in,
                              void* d_out, int out_size, void* d_ws, size_t ws_size,
                              hipStream_t stream) {
    const float* x  = (const float*)d_in[0];
    const float* wg = (const float*)d_in[1];
    const float* bg = (const float*)d_in[2];
    const float* wt = (const float*)d_in[3];
    const float* bt = (const float*)d_in[4];
    const float* wp = (const float*)d_in[5];
    const float* bp = (const float*)d_in[6];
    const float* wo = (const float*)d_in[7];
    const float* bo = (const float*)d_in[8];
    char* ws = (char*)d_ws;
    float* y = (float*)d_out;

    // split-KV factor: 4 if workspace allows, else 2 (partials overlay XT)
    unsigned long long need4 = OFF_END + (16ull << 20) + (1ull << 20);
    int nchunk;
    unsigned long long off_part, off_ml;
    if (ws_size >= need4) {
        nchunk = 4; off_part = OFF_END; off_ml = OFF_END + (16ull << 20);
    } else {
        nchunk = 2; off_part = OFF_XT; off_ml = OFF_END;
    }

    prep_weights<<<256, 256, 0, stream>>>(wg, bg, wt, bt, wp, bp, wo, bo, ws);
    transpose_x<<<dim3(128, 8, 4), 256, 0, stream>>>(x, ws);
    gemm_qk<<<dim3(64, 4, 4), 256, 0, stream>>>(ws);
    gemm_g<<<dim3(64, 2, 4), 256, 0, stream>>>(ws);
    flash2<<<dim3(nchunk == 4 ? 512 : 256), 256, 0, stream>>>(ws, nchunk, off_part, off_ml);
    if (nchunk == 4) combine<4><<<1024, 256, 0, stream>>>(ws, off_part, off_ml);
    else             combine<2><<<1024, 256, 0, stream>>>(ws, off_part, off_ml);
    gemm_out<<<dim3(64, 4, 4), 256, 0, stream>>>(x, ws, y);
}

// Round 3
// 164.307 us; speedup vs baseline: 2.5334x; 1.2999x over previous
//
#include <hip/hip_runtime.h>
#include <hip/hip_bf16.h>

// NonLocal block == flash attention (4 heads, N=4096, D=128) + 1x1-conv GEMMs.
// Round 3: K staged in LDS (global_load_lds, dbuf, swizzled), V direct from L2,
// KVBLK=32, split-KV x8, defer-max rescale.

typedef float f32x4 __attribute__((ext_vector_type(4)));
typedef short s16x8 __attribute__((ext_vector_type(8)));

#define B_  4
#define C_  256
#define CI_ 128
#define N_  4096

// workspace layout (bytes)
#define OFF_XT   0ull                    // bf16 [B][N][C]   8 MB
#define OFF_Q    (8ull  << 20)           // bf16 [B][N][CI]  4 MB (theta^T, scaled)
#define OFF_K    (12ull << 20)           // bf16 [B][N][CI]  4 MB (phi^T)
#define OFF_G    (16ull << 20)           // bf16 [B][CI][N]  4 MB (g, V^T layout)
#define OFF_O    (20ull << 20)           // bf16 [B][N][CI]  4 MB (combined attn out)
#define OFF_WQK  (24ull << 20)
#define OFF_WG   (OFF_WQK + 131072)
#define OFF_WOUT (OFF_WG  + 65536)
#define OFF_BQK  (OFF_WOUT + 65536)
#define OFF_BG   (OFF_BQK + 1024)
#define OFF_BOUT (OFF_BG  + 512)
#define OFF_END  (OFF_BOUT + 1024)       // = 25430528

__device__ inline f32x4 mfma16(s16x8 a, s16x8 b, f32x4 c) {
    return __builtin_amdgcn_mfma_f32_16x16x32_bf16(a, b, c, 0, 0, 0);
}
__device__ inline s16x8 ld8(const __hip_bfloat16* p) { return *(const s16x8*)p; }
__device__ inline float b2f(short u) {
    return __uint_as_float(((unsigned int)(unsigned short)u) << 16);
}
__device__ inline unsigned int pk2(float a, float b) {
    __hip_bfloat162 h;
    h.x = __float2bfloat16(a); h.y = __float2bfloat16(b);
    return *(unsigned int*)&h;
}
__device__ inline void gload_lds16(const void* g, void* l) {
    __builtin_amdgcn_global_load_lds(
        (const __attribute__((address_space(1))) unsigned int*)g,
        (__attribute__((address_space(3))) unsigned int*)l, 16, 0, 0);
}

// ---------------- weight prep: fp32 -> bf16; fold log2e/sqrt(Ci) into theta
__global__ void prep_weights(const float* wg, const float* bg,
                             const float* wt, const float* bt,
                             const float* wp, const float* bp,
                             const float* wo, const float* bo, char* ws) {
    __hip_bfloat16* Wqk  = (__hip_bfloat16*)(ws + OFF_WQK);
    __hip_bfloat16* Wg   = (__hip_bfloat16*)(ws + OFF_WG);
    __hip_bfloat16* Wout = (__hip_bfloat16*)(ws + OFF_WOUT);
    float* Bqk  = (float*)(ws + OFF_BQK);
    float* Bg   = (float*)(ws + OFF_BG);
    float* Bout = (float*)(ws + OFF_BOUT);
    const float rs = 0.08838834764831845f * 1.4426950408889634f;  // 1/sqrt(128)*log2(e)
    int idx = blockIdx.x * 256 + threadIdx.x;
    if (idx < 65536) {
        int r = idx >> 8, c = idx & 255;
        float v = (r < 128) ? wt[r * 256 + c] * rs : wp[(r - 128) * 256 + c];
        Wqk[idx] = __float2bfloat16(v);
    }
    if (idx < 32768) {
        Wg[idx]   = __float2bfloat16(wg[idx]);
        Wout[idx] = __float2bfloat16(wo[idx]);
    }
    if (idx < 256) { Bqk[idx] = (idx < 128) ? bt[idx] * rs : bp[idx - 128]; Bout[idx] = bo[idx]; }
    if (idx < 128) Bg[idx] = bg[idx];
}

// ---------------- x [B][C][N] f32 -> XT [B][N][C] bf16 -------------------
__global__ __launch_bounds__(256) void transpose_x(const float* x, char* ws) {
    __shared__ float tile[32][33];
    __hip_bfloat16* XT = (__hip_bfloat16*)(ws + OFF_XT);
    int b = blockIdx.z;
    int n0 = blockIdx.x * 32, c0 = blockIdx.y * 32;
    int tx = threadIdx.x & 31, ty = threadIdx.x >> 5;
#pragma unroll
    for (int r = 0; r < 4; r++)
        tile[ty + 8 * r][tx] = x[(size_t)(b * C_ + c0 + ty + 8 * r) * N_ + n0 + tx];
    __syncthreads();
#pragma unroll
    for (int r = 0; r < 4; r++)
        XT[(size_t)(b * N_ + n0 + ty + 8 * r) * C_ + c0 + tx] =
            __float2bfloat16(tile[tx][ty + 8 * r]);
}

// ---------------- Q/K projection ------------------------------------------
__global__ __launch_bounds__(256) void gemm_qk(char* ws) {
    const __hip_bfloat16* XT = (const __hip_bfloat16*)(ws + OFF_XT);
    const __hip_bfloat16* W  = (const __hip_bfloat16*)(ws + OFF_WQK);
    const float* Bias = (const float*)(ws + OFF_BQK);
    __hip_bfloat16* Q  = (__hip_bfloat16*)(ws + OFF_Q);
    __hip_bfloat16* Kb = (__hip_bfloat16*)(ws + OFF_K);
    int b = blockIdx.z;
    int w = threadIdx.x >> 6, l = threadIdx.x & 63, lr = l & 15, lg = l >> 4;
    int n0 = blockIdx.x * 64 + w * 16;
    int o0 = blockIdx.y * 64;
    f32x4 acc[4] = {};
    const __hip_bfloat16* Arow = XT + (size_t)(b * N_ + n0 + lr) * C_ + lg * 8;
#pragma unroll
    for (int kk = 0; kk < 8; kk++) {
        s16x8 a = ld8(Arow + kk * 32);
#pragma unroll
        for (int f = 0; f < 4; f++) {
            s16x8 bb = ld8(W + (size_t)(o0 + 16 * f + lr) * C_ + kk * 32 + lg * 8);
            acc[f] = mfma16(a, bb, acc[f]);
        }
    }
#pragma unroll
    for (int f = 0; f < 4; f++) {
        int o = o0 + 16 * f + lr;
        float bias = Bias[o];
#pragma unroll
        for (int i = 0; i < 4; i++) {
            int n = n0 + lg * 4 + i;
            float v = acc[f][i] + bias;
            if (o < 128) Q [(size_t)(b * N_ + n) * CI_ + o]         = __float2bfloat16(v);
            else         Kb[(size_t)(b * N_ + n) * CI_ + (o - 128)] = __float2bfloat16(v);
        }
    }
}

// ---------------- g projection --------------------------------------------
__global__ __launch_bounds__(256) void gemm_g(char* ws) {
    const __hip_bfloat16* XT = (const __hip_bfloat16*)(ws + OFF_XT);
    const __hip_bfloat16* Wg = (const __hip_bfloat16*)(ws + OFF_WG);
    const float* Bg = (const float*)(ws + OFF_BG);
    __hip_bfloat16* G = (__hip_bfloat16*)(ws + OFF_G);
    int b = blockIdx.z;
    int w = threadIdx.x >> 6, l = threadIdx.x & 63, lr = l & 15, lg = l >> 4;
    int o0 = blockIdx.y * 64 + w * 16;
    int n0 = blockIdx.x * 64;
    f32x4 acc[4] = {};
#pragma unroll
    for (int kk = 0; kk < 8; kk++) {
        s16x8 a = ld8(Wg + (size_t)(o0 + lr) * C_ + kk * 32 + lg * 8);
#pragma unroll
        for (int f = 0; f < 4; f++) {
            s16x8 bb = ld8(XT + (size_t)(b * N_ + n0 + 16 * f + lr) * C_ + kk * 32 + lg * 8);
            acc[f] = mfma16(a, bb, acc[f]);
        }
    }
#pragma unroll
    for (int f = 0; f < 4; f++) {
#pragma unroll
        for (int i = 0; i < 4; i++) {
            int o = o0 + lg * 4 + i;
            int n = n0 + 16 * f + lr;
            G[(size_t)(b * CI_ + o) * N_ + n] = __float2bfloat16(acc[f][i] + Bg[o]);
        }
    }
}

// ---------------- flash v3: LDS-staged K (dbuf), V from L2, KVBLK=32 -------
// grid: 128*nchunk blocks of 256 (4 waves). Wave = 32 q-rows. Per block the 4
// waves share the K tile via global_load_lds (linear LDS dest, inverse-swizzled
// global source; reads apply the same XOR swizzle).
__global__ __launch_bounds__(256) void flash3(char* ws, int nchunk,
                                              unsigned long long off_part,
                                              unsigned long long off_ml) {
    const __hip_bfloat16* Q  = (const __hip_bfloat16*)(ws + OFF_Q);
    const __hip_bfloat16* Kb = (const __hip_bfloat16*)(ws + OFF_K);
    const __hip_bfloat16* G  = (const __hip_bfloat16*)(ws + OFF_G);
    __hip_bfloat16* OP = (__hip_bfloat16*)(ws + off_part);
    float* ML = (float*)(ws + off_ml);

    __shared__ char kbuf[2][32 * 256];   // 2 x 8 KB : K tile [32 j][256 B]
    __shared__ char pbuf[4][2][2048];    // per-wave P staging (row stride 128 B)

    int L = blockIdx.x;
    int pair, qt, b, cz;
    if (nchunk == 8)      { pair = L & 31; qt = L >> 5; b = pair >> 3; cz = pair & 7; }
    else if (nchunk == 4) { pair = L & 15; qt = L >> 4; b = pair >> 2; cz = pair & 3; }
    else                  { pair = L & 7;  qt = L >> 3; b = pair >> 1; cz = pair & 1; }
    int CH = N_ / nchunk;
    int jb = cz * CH, je = jb + CH;

    int w = threadIdx.x >> 6, l = threadIdx.x & 63, lr = l & 15, lg = l >> 4;
    int q0 = qt * 128 + w * 32;
    int swz = (lr & 7) << 4;
    char* pw = &pbuf[w][0][0];

    // stage K rows [w*8, w*8+8) of tile j0 into kbuf[pb] (2 x 1KB issues/wave)
    auto STAGE = [&](int pb, int j0) {
#pragma unroll
        for (int i = 0; i < 2; i++) {
            int row = w * 8 + i * 4 + (l >> 4);
            int bcol = ((l & 15) << 4) ^ ((row & 7) << 4);
            const char* src = (const char*)Kb + (((size_t)b * N_ + j0 + row) << 8) + bcol;
            gload_lds16(src, &kbuf[pb][(w * 8 + i * 4) * 256]);
        }
    };

    // Q as B-operand: lane holds Q[k = kk*32+lg*8+e][col q = q0+16qf+lr]
    s16x8 qa[2][4];
#pragma unroll
    for (int qf = 0; qf < 2; qf++) {
        const __hip_bfloat16* qrow = Q + ((size_t)b * N_ + q0 + 16 * qf + lr) * CI_ + lg * 8;
#pragma unroll
        for (int kk = 0; kk < 4; kk++) qa[qf][kk] = ld8(qrow + kk * 32);
    }

    f32x4 oacc[2][8] = {};
    float m_i[2] = {-1e30f, -1e30f}, l_i[2] = {0.f, 0.f};

    STAGE(0, jb);
    __syncthreads();
    int pb = 0;

    for (int j0 = jb; j0 < je; j0 += 32) {
        if (j0 + 32 < je) STAGE(pb ^ 1, j0 + 32);
        const char* kb = kbuf[pb];
        // S^T = K Q  (swapped: lane owns 16 j of one q per qf)
        f32x4 s[2][2] = {};
#pragma unroll
        for (int kk = 0; kk < 4; kk++) {
            int bc = ((kk << 6) + (lg << 4)) ^ swz;
            s16x8 kf0 = *(const s16x8*)(kb + lr * 256 + bc);
            s16x8 kf1 = *(const s16x8*)(kb + (16 + lr) * 256 + bc);
            s[0][0] = mfma16(kf0, qa[0][kk], s[0][0]);
            s[1][0] = mfma16(kf0, qa[1][kk], s[1][0]);
            s[0][1] = mfma16(kf1, qa[0][kk], s[0][1]);
            s[1][1] = mfma16(kf1, qa[1][kk], s[1][1]);
        }
#pragma unroll
        for (int qf = 0; qf < 2; qf++) {
            // row max (lane-local 8 + 2 shuffles)
            f32x4 m4;
            m4[0] = fmaxf(s[qf][0][0], s[qf][1][0]); m4[1] = fmaxf(s[qf][0][1], s[qf][1][1]);
            m4[2] = fmaxf(s[qf][0][2], s[qf][1][2]); m4[3] = fmaxf(s[qf][0][3], s[qf][1][3]);
            float tm = fmaxf(fmaxf(m4[0], m4[1]), fmaxf(m4[2], m4[3]));
            tm = fmaxf(tm, __shfl_xor(tm, 16));
            tm = fmaxf(tm, __shfl_xor(tm, 32));
            // defer-max: only rescale when the running max grew by > 8 (log2)
            if (!__all(tm <= m_i[qf] + 8.f)) {
                float mn = fmaxf(m_i[qf], tm);
                float al = exp2f(m_i[qf] - mn);
                m_i[qf] = mn;
                f32x4 a4;
#pragma unroll
                for (int i = 0; i < 4; i++) a4[i] = __shfl(al, lg * 4 + i);
#pragma unroll
                for (int cf = 0; cf < 8; cf++) oacc[qf][cf] *= a4;
                l_i[qf] *= al;
            }
            float mref = m_i[qf];
            f32x4 sum4 = {};
#pragma unroll
            for (int t = 0; t < 2; t++) {
#pragma unroll
                for (int i = 0; i < 4; i++) s[qf][t][i] = exp2f(s[qf][t][i] - mref);
                sum4 += s[qf][t];
            }
            float rs = (sum4[0] + sum4[1]) + (sum4[2] + sum4[3]);
            rs += __shfl_xor(rs, 16);
            rs += __shfl_xor(rs, 32);
            l_i[qf] += rs;
            // pack P -> pbuf (row = q = lr, swizzled)
            char* base = pw + qf * 2048 + lr * 128;
#pragma unroll
            for (int t = 0; t < 2; t++) {
                unsigned int lo = pk2(s[qf][t][0], s[qf][t][1]);
                unsigned int hi = pk2(s[qf][t][2], s[qf][t][3]);
                int byte0 = ((t << 5) + (lg << 3)) ^ swz;
                *(unsigned int*)(base + byte0)     = lo;
                *(unsigned int*)(base + byte0 + 4) = hi;
            }
        }
        // P fragments (A-operand: row q = lr, k = j = lg*8+e)
        s16x8 pa0 = *(const s16x8*)(pw + lr * 128 + ((lg << 4) ^ swz));
        s16x8 pa1 = *(const s16x8*)(pw + 2048 + lr * 128 + ((lg << 4) ^ swz));
        // PV: V direct from L2 (independent loads pipeline under softmax)
#pragma unroll
        for (int cf = 0; cf < 8; cf++) {
            s16x8 vb = ld8(G + ((size_t)b * CI_ + 16 * cf + lr) * N_ + j0 + lg * 8);
            oacc[0][cf] = mfma16(pa0, vb, oacc[0][cf]);
            oacc[1][cf] = mfma16(pa1, vb, oacc[1][cf]);
        }
        __syncthreads();
        pb ^= 1;
    }
    // write unnormalized partial O + (m,l)
#pragma unroll
    for (int qf = 0; qf < 2; qf++) {
#pragma unroll
        for (int i = 0; i < 4; i++) {
            size_t row = ((size_t)(cz * B_ + b) * N_ + q0 + 16 * qf + lg * 4 + i) * CI_;
#pragma unroll
            for (int cf = 0; cf < 8; cf++)
                OP[row + 16 * cf + lr] = __float2bfloat16(oacc[qf][cf][i]);
        }
        if (lg == 0) {
            size_t mi = ((size_t)(cz * B_ + b) * N_ + q0 + 16 * qf + lr) * 2;
            ML[mi] = m_i[qf];
            ML[mi + 1] = l_i[qf];
        }
    }
}

// ---------------- combine split-KV partials -> O ---------------------------
template <int NC>
__global__ __launch_bounds__(256) void combine(char* ws,
                                               unsigned long long off_part,
                                               unsigned long long off_ml) {
    const __hip_bfloat16* OP = (const __hip_bfloat16*)(ws + off_part);
    const float* ML = (const float*)(ws + off_ml);
    __hip_bfloat16* O = (__hip_bfloat16*)(ws + OFF_O);
    int idx = blockIdx.x * 256 + threadIdx.x;      // B*N*16 threads
    int cg = idx & 15, n = (idx >> 4) & (N_ - 1), b = idx >> 16;
    float mz[NC], lz[NC], M = -1e30f;
#pragma unroll
    for (int z = 0; z < NC; z++) {
        size_t mi = ((size_t)(z * B_ + b) * N_ + n) * 2;
        mz[z] = ML[mi]; lz[z] = ML[mi + 1];
        M = fmaxf(M, mz[z]);
    }
    float Lsum = 0.f, wz[NC];
#pragma unroll
    for (int z = 0; z < NC; z++) { wz[z] = exp2f(mz[z] - M); Lsum += lz[z] * wz[z]; }
    float inv = 1.f / Lsum;
    float o[8] = {};
#pragma unroll
    for (int z = 0; z < NC; z++) {
        s16x8 v = ld8(OP + ((size_t)(z * B_ + b) * N_ + n) * CI_ + cg * 8);
#pragma unroll
        for (int i = 0; i < 8; i++) o[i] += wz[z] * b2f(v[i]);
    }
    s16x8 r;
#pragma unroll
    for (int i = 0; i < 8; i++) {
        __hip_bfloat16 h = __float2bfloat16(o[i] * inv);
        r[i] = *(short*)&h;
    }
    *(s16x8*)(O + ((size_t)b * N_ + n) * CI_ + cg * 8) = r;
}

// ---------------- out projection + bias + residual -------------------------
__global__ __launch_bounds__(256) void gemm_out(const float* x, char* ws, float* y) {
    const __hip_bfloat16* Ob = (const __hip_bfloat16*)(ws + OFF_O);
    const __hip_bfloat16* Wo = (const __hip_bfloat16*)(ws + OFF_WOUT);
    const float* Bout = (const float*)(ws + OFF_BOUT);
    int b = blockIdx.z;
    int w = threadIdx.x >> 6, l = threadIdx.x & 63, lr = l & 15, lg = l >> 4;
    int o0 = blockIdx.y * 64 + w * 16;
    int n0 = blockIdx.x * 64;
    f32x4 acc[4] = {};
#pragma unroll
    for (int kk = 0; kk < 4; kk++) {
        s16x8 a = ld8(Wo + (size_t)(o0 + lr) * CI_ + kk * 32 + lg * 8);
#pragma unroll
        for (int f = 0; f < 4; f++) {
            s16x8 bb = ld8(Ob + (size_t)(b * N_ + n0 + 16 * f + lr) * CI_ + kk * 32 + lg * 8);
            acc[f] = mfma16(a, bb, acc[f]);
        }
    }
#pragma unroll
    for (int f = 0; f < 4; f++) {
#pragma unroll
        for (int i = 0; i < 4; i++) {
            int o = o0 + lg * 4 + i;
            int n = n0 + 16 * f + lr;
            size_t idx = (size_t)(b * C_ + o) * N_ + n;
            y[idx] = acc[f][i] + Bout[o] + x[idx];
        }
    }
}

extern "C" void kernel_launch(void* const* d_in, const int* in_sizes, int n_in,
                              void* d_out, int out_size, void* d_ws, size_t ws_size,
                              hipStream_t stream) {
    const float* x  = (const float*)d_in[0];
    const float* wg = (const float*)d_in[1];
    const float* bg = (const float*)d_in[2];
    const float* wt = (const float*)d_in[3];
    const float* bt = (const float*)d_in[4];
    const float* wp = (const float*)d_in[5];
    const float* bp = (const float*)d_in[6];
    const float* wo = (const float*)d_in[7];
    const float* bo = (const float*)d_in[8];
    char* ws = (char*)d_ws;
    float* y = (float*)d_out;

    // split-KV factor, adaptive on workspace size
    unsigned long long need8 = OFF_END + (32ull << 20) + (2ull << 20);
    unsigned long long need4 = OFF_END + (16ull << 20) + (1ull << 20);
    int nchunk;
    unsigned long long off_part, off_ml;
    if (ws_size >= need8) {
        nchunk = 8; off_part = OFF_END; off_ml = OFF_END + (32ull << 20);
    } else if (ws_size >= need4) {
        nchunk = 4; off_part = OFF_END; off_ml = OFF_END + (16ull << 20);
    } else {
        nchunk = 2; off_part = OFF_XT; off_ml = OFF_END;
    }

    prep_weights<<<256, 256, 0, stream>>>(wg, bg, wt, bt, wp, bp, wo, bo, ws);
    transpose_x<<<dim3(128, 8, 4), 256, 0, stream>>>(x, ws);
    gemm_qk<<<dim3(64, 4, 4), 256, 0, stream>>>(ws);
    gemm_g<<<dim3(64, 2, 4), 256, 0, stream>>>(ws);
    flash3<<<dim3(128 * nchunk), 256, 0, stream>>>(ws, nchunk, off_part, off_ml);
    if (nchunk == 8)      combine<8><<<1024, 256, 0, stream>>>(ws, off_part, off_ml);
    else if (nchunk == 4) combine<4><<<1024, 256, 0, stream>>>(ws, off_part, off_ml);
    else                  combine<2><<<1024, 256, 0, stream>>>(ws, off_part, off_ml);
    gemm_out<<<dim3(64, 4, 4), 256, 0, stream>>>(x, ws, y);
}

// Round 4
// 155.644 us; speedup vs baseline: 2.6744x; 1.0557x over previous
//
#include <hip/hip_runtime.h>
#include <hip/hip_bf16.h>

// NonLocal block == flash attention (4 heads, N=4096, D=128) + 1x1-conv GEMMs.
// Round 4: V staged in LDS (dbuf, swizzled) alongside K; fused proj kernel
// (Q,K,G in one pass over XT); gemm_out single-pass over O; raw v_exp_f32.

typedef float f32x4 __attribute__((ext_vector_type(4)));
typedef short s16x8 __attribute__((ext_vector_type(8)));

#define B_  4
#define C_  256
#define CI_ 128
#define N_  4096

// workspace layout (bytes)
#define OFF_XT   0ull                    // bf16 [B][N][C]   8 MB
#define OFF_Q    (8ull  << 20)           // bf16 [B][N][CI]  4 MB (theta^T, scaled)
#define OFF_K    (12ull << 20)           // bf16 [B][N][CI]  4 MB (phi^T)
#define OFF_G    (16ull << 20)           // bf16 [B][CI][N]  4 MB (g, V^T layout)
#define OFF_O    (20ull << 20)           // bf16 [B][N][CI]  4 MB (combined attn out)
#define OFF_WQK  (24ull << 20)
#define OFF_WG   (OFF_WQK + 131072)
#define OFF_WOUT (OFF_WG  + 65536)
#define OFF_BQK  (OFF_WOUT + 65536)
#define OFF_BG   (OFF_BQK + 1024)
#define OFF_BOUT (OFF_BG  + 512)
#define OFF_END  (OFF_BOUT + 1024)       // = 25430528

__device__ inline f32x4 mfma16(s16x8 a, s16x8 b, f32x4 c) {
    return __builtin_amdgcn_mfma_f32_16x16x32_bf16(a, b, c, 0, 0, 0);
}
__device__ inline s16x8 ld8(const __hip_bfloat16* p) { return *(const s16x8*)p; }
__device__ inline float b2f(short u) {
    return __uint_as_float(((unsigned int)(unsigned short)u) << 16);
}
__device__ inline unsigned int pk2(float a, float b) {
    __hip_bfloat162 h;
    h.x = __float2bfloat16(a); h.y = __float2bfloat16(b);
    return *(unsigned int*)&h;
}
__device__ inline void gload_lds16(const void* g, void* l) {
    __builtin_amdgcn_global_load_lds(
        (const __attribute__((address_space(1))) unsigned int*)g,
        (__attribute__((address_space(3))) unsigned int*)l, 16, 0, 0);
}
__device__ inline float fexp2(float x) { return __builtin_amdgcn_exp2f(x); }

// ---------------- weight prep: fp32 -> bf16; fold log2e/sqrt(Ci) into theta
__global__ void prep_weights(const float* wg, const float* bg,
                             const float* wt, const float* bt,
                             const float* wp, const float* bp,
                             const float* wo, const float* bo, char* ws) {
    __hip_bfloat16* Wqk  = (__hip_bfloat16*)(ws + OFF_WQK);
    __hip_bfloat16* Wg   = (__hip_bfloat16*)(ws + OFF_WG);
    __hip_bfloat16* Wout = (__hip_bfloat16*)(ws + OFF_WOUT);
    float* Bqk  = (float*)(ws + OFF_BQK);
    float* Bg   = (float*)(ws + OFF_BG);
    float* Bout = (float*)(ws + OFF_BOUT);
    const float rs = 0.08838834764831845f * 1.4426950408889634f;  // 1/sqrt(128)*log2(e)
    int idx = blockIdx.x * 256 + threadIdx.x;
    if (idx < 65536) {
        int r = idx >> 8, c = idx & 255;
        float v = (r < 128) ? wt[r * 256 + c] * rs : wp[(r - 128) * 256 + c];
        Wqk[idx] = __float2bfloat16(v);
    }
    if (idx < 32768) {
        Wg[idx]   = __float2bfloat16(wg[idx]);
        Wout[idx] = __float2bfloat16(wo[idx]);
    }
    if (idx < 256) { Bqk[idx] = (idx < 128) ? bt[idx] * rs : bp[idx - 128]; Bout[idx] = bo[idx]; }
    if (idx < 128) Bg[idx] = bg[idx];
}

// ---------------- x [B][C][N] f32 -> XT [B][N][C] bf16 -------------------
__global__ __launch_bounds__(256) void transpose_x(const float* x, char* ws) {
    __shared__ float tile[32][33];
    __hip_bfloat16* XT = (__hip_bfloat16*)(ws + OFF_XT);
    int b = blockIdx.z;
    int n0 = blockIdx.x * 32, c0 = blockIdx.y * 32;
    int tx = threadIdx.x & 31, ty = threadIdx.x >> 5;
#pragma unroll
    for (int r = 0; r < 4; r++)
        tile[ty + 8 * r][tx] = x[(size_t)(b * C_ + c0 + ty + 8 * r) * N_ + n0 + tx];
    __syncthreads();
#pragma unroll
    for (int r = 0; r < 4; r++)
        XT[(size_t)(b * N_ + n0 + ty + 8 * r) * C_ + c0 + tx] =
            __float2bfloat16(tile[tx][ty + 8 * r]);
}

// ---------------- fused projection: Q, K, G from XT in one pass ------------
// grid (128, B_), block 256 (4 waves). Block = 32 n-rows; XT tile (16 KB)
// staged via global_load_lds with XOR-swizzled source. One lane fetch serves
// as A-operand (Q/K path, row=n) and B-operand (G path, col=n).
__global__ __launch_bounds__(256) void proj(char* ws) {
    const __hip_bfloat16* XT  = (const __hip_bfloat16*)(ws + OFF_XT);
    const __hip_bfloat16* Wqk = (const __hip_bfloat16*)(ws + OFF_WQK);
    const __hip_bfloat16* Wg  = (const __hip_bfloat16*)(ws + OFF_WG);
    const float* Bqk = (const float*)(ws + OFF_BQK);
    const float* Bg  = (const float*)(ws + OFF_BG);
    __hip_bfloat16* Q  = (__hip_bfloat16*)(ws + OFF_Q);
    __hip_bfloat16* Kb = (__hip_bfloat16*)(ws + OFF_K);
    __hip_bfloat16* G  = (__hip_bfloat16*)(ws + OFF_G);

    __shared__ char at[32 * 512];   // [32 n][256 c] bf16, 16B slots XOR-swizzled

    int b = blockIdx.y, n0 = blockIdx.x * 32;
    int w = threadIdx.x >> 6, l = threadIdx.x & 63, lr = l & 15, lg = l >> 4;

    const char* xbase = (const char*)(XT + ((size_t)b * N_ + n0) * C_);
#pragma unroll
    for (int p = 0; p < 4; p++) {
        int row = p * 8 + w * 2 + (l >> 5);
        int slot = l & 31;
        const char* src = xbase + row * 512 + ((slot ^ (row & 7)) << 4);
        gload_lds16(src, &at[(p * 8 + w * 2) * 512]);
    }
    __syncthreads();

    f32x4 acc[4][2] = {};    // QK path: [of][nf]
    f32x4 accg[2][2] = {};   // G  path: [og][nf]
    int o0q = w * 64, o0g = w * 32;
#pragma unroll
    for (int kk = 0; kk < 8; kk++) {
        s16x8 a[2];
#pragma unroll
        for (int nf = 0; nf < 2; nf++) {
            int row = nf * 16 + lr;
            int s = (4 * kk + lg) ^ (row & 7);
            a[nf] = *(const s16x8*)(&at[row * 512 + s * 16]);
        }
#pragma unroll
        for (int of = 0; of < 4; of++) {
            s16x8 bb = ld8(Wqk + (size_t)(o0q + 16 * of + lr) * C_ + kk * 32 + lg * 8);
            acc[of][0] = mfma16(a[0], bb, acc[of][0]);
            acc[of][1] = mfma16(a[1], bb, acc[of][1]);
        }
#pragma unroll
        for (int og = 0; og < 2; og++) {
            s16x8 ag = ld8(Wg + (size_t)(o0g + 16 * og + lr) * C_ + kk * 32 + lg * 8);
            accg[og][0] = mfma16(ag, a[0], accg[og][0]);
            accg[og][1] = mfma16(ag, a[1], accg[og][1]);
        }
    }
    // QK epilogue: D col(lr)=o, row(lg*4+i)=n
#pragma unroll
    for (int of = 0; of < 4; of++) {
        int o = o0q + 16 * of + lr;
        float bias = Bqk[o];
#pragma unroll
        for (int nf = 0; nf < 2; nf++) {
#pragma unroll
            for (int i = 0; i < 4; i++) {
                int n = n0 + 16 * nf + lg * 4 + i;
                float v = acc[of][nf][i] + bias;
                if (o < 128) Q [(size_t)(b * N_ + n) * CI_ + o]         = __float2bfloat16(v);
                else         Kb[(size_t)(b * N_ + n) * CI_ + (o - 128)] = __float2bfloat16(v);
            }
        }
    }
    // G epilogue: D col(lr)=n, row(lg*4+i)=o
#pragma unroll
    for (int og = 0; og < 2; og++) {
#pragma unroll
        for (int i = 0; i < 4; i++) {
            int o = o0g + 16 * og + lg * 4 + i;
            float bias = Bg[o];
#pragma unroll
            for (int nf = 0; nf < 2; nf++) {
                int n = n0 + 16 * nf + lr;
                G[(size_t)(b * CI_ + o) * N_ + n] = __float2bfloat16(accg[og][nf][i] + bias);
            }
        }
    }
}

// ---------------- flash v4: K AND V staged in LDS (dbuf, swizzled) ---------
// grid: 128*nchunk blocks of 256 (4 waves); wave = 32 q-rows, KVBLK=32.
__global__ __launch_bounds__(256, 4) void flash4(char* ws, int nchunk,
                                                 unsigned long long off_part,
                                                 unsigned long long off_ml) {
    const __hip_bfloat16* Q  = (const __hip_bfloat16*)(ws + OFF_Q);
    const __hip_bfloat16* Kb = (const __hip_bfloat16*)(ws + OFF_K);
    const __hip_bfloat16* G  = (const __hip_bfloat16*)(ws + OFF_G);
    __hip_bfloat16* OP = (__hip_bfloat16*)(ws + off_part);
    float* ML = (float*)(ws + off_ml);

    __shared__ char kbuf[2][32 * 256];   // K tile [32 j][256 B], swizzled slots
    __shared__ char vbuf[2][128 * 64];   // V tile [128 c][64 B], swizzled slots
    __shared__ char pbuf[4][2048];       // per-wave P staging (qf-sequential)

    int L = blockIdx.x;
    int pair, qt, b, cz;
    if (nchunk == 8)      { pair = L & 31; qt = L >> 5; b = pair >> 3; cz = pair & 7; }
    else if (nchunk == 4) { pair = L & 15; qt = L >> 4; b = pair >> 2; cz = pair & 3; }
    else                  { pair = L & 7;  qt = L >> 3; b = pair >> 1; cz = pair & 1; }
    int CH = N_ / nchunk;
    int jb = cz * CH, je = jb + CH;

    int w = threadIdx.x >> 6, l = threadIdx.x & 63, lr = l & 15, lg = l >> 4;
    int q0 = qt * 128 + w * 32;
    int swz = (lr & 7) << 4;
    char* pw = &pbuf[w][0];

    // stage K rows (8/wave) + V c-rows (32/wave) of tile j0 into buffers[pb]
    auto STAGE = [&](int pb_, int j0_) {
#pragma unroll
        for (int i = 0; i < 2; i++) {
            int row = w * 8 + i * 4 + (l >> 4);
            int bcol = ((l & 15) << 4) ^ ((row & 7) << 4);
            const char* src = (const char*)Kb + (((size_t)b * N_ + j0_ + row) << 8) + bcol;
            gload_lds16(src, &kbuf[pb_][(w * 8 + i * 4) * 256]);
        }
#pragma unroll
        for (int i = 0; i < 2; i++) {
            int c = w * 32 + i * 16 + (l >> 2);
            int joct = l & 3;
            const char* src = (const char*)G + ((((size_t)b * CI_ + c) * N_ + j0_) << 1)
                              + ((joct ^ (c & 3)) << 4);
            gload_lds16(src, &vbuf[pb_][(w * 32 + i * 16) * 64]);
        }
    };

    // Q as B-operand: lane holds Q[k = kk*32+lg*8+e][col q = q0+16qf+lr]
    s16x8 qa[2][4];
#pragma unroll
    for (int qf = 0; qf < 2; qf++) {
        const __hip_bfloat16* qrow = Q + ((size_t)b * N_ + q0 + 16 * qf + lr) * CI_ + lg * 8;
#pragma unroll
        for (int kk = 0; kk < 4; kk++) qa[qf][kk] = ld8(qrow + kk * 32);
    }

    f32x4 oacc[2][8] = {};
    float m_i[2] = {-1e30f, -1e30f}, l_i[2] = {0.f, 0.f};

    STAGE(0, jb);
    __syncthreads();
    int pb = 0;

    for (int j0 = jb; j0 < je; j0 += 32) {
        if (j0 + 32 < je) STAGE(pb ^ 1, j0 + 32);
        const char* kb = kbuf[pb];
        const char* vbb = vbuf[pb];
        // S^T = K Q  (swapped: lane owns 16 j of one q per qf)
        f32x4 s[2][2] = {};
#pragma unroll
        for (int kk = 0; kk < 4; kk++) {
            int bc = ((kk << 6) + (lg << 4)) ^ swz;
            s16x8 kf0 = *(const s16x8*)(kb + lr * 256 + bc);
            s16x8 kf1 = *(const s16x8*)(kb + (16 + lr) * 256 + bc);
            s[0][0] = mfma16(kf0, qa[0][kk], s[0][0]);
            s[1][0] = mfma16(kf0, qa[1][kk], s[1][0]);
            s[0][1] = mfma16(kf1, qa[0][kk], s[0][1]);
            s[1][1] = mfma16(kf1, qa[1][kk], s[1][1]);
        }
        s16x8 pa[2];
#pragma unroll
        for (int qf = 0; qf < 2; qf++) {
            f32x4 m4;
            m4[0] = fmaxf(s[qf][0][0], s[qf][1][0]); m4[1] = fmaxf(s[qf][0][1], s[qf][1][1]);
            m4[2] = fmaxf(s[qf][0][2], s[qf][1][2]); m4[3] = fmaxf(s[qf][0][3], s[qf][1][3]);
            float tm = fmaxf(fmaxf(m4[0], m4[1]), fmaxf(m4[2], m4[3]));
            tm = fmaxf(tm, __shfl_xor(tm, 16));
            tm = fmaxf(tm, __shfl_xor(tm, 32));
            // defer-max: rescale only when running max grew by > 8 (log2)
            if (!__all(tm <= m_i[qf] + 8.f)) {
                float mn = fmaxf(m_i[qf], tm);
                float al = fexp2(m_i[qf] - mn);
                m_i[qf] = mn;
                f32x4 a4;
#pragma unroll
                for (int i = 0; i < 4; i++) a4[i] = __shfl(al, lg * 4 + i);
#pragma unroll
                for (int cf = 0; cf < 8; cf++) oacc[qf][cf] *= a4;
                l_i[qf] *= al;
            }
            float mref = m_i[qf];
            f32x4 sum4 = {};
#pragma unroll
            for (int t = 0; t < 2; t++) {
#pragma unroll
                for (int i = 0; i < 4; i++) s[qf][t][i] = fexp2(s[qf][t][i] - mref);
                sum4 += s[qf][t];
            }
            float rs = (sum4[0] + sum4[1]) + (sum4[2] + sum4[3]);
            rs += __shfl_xor(rs, 16);
            rs += __shfl_xor(rs, 32);
            l_i[qf] += rs;
            // pack P -> pbuf (row = q = lr, swizzled); reused across qf
            char* base = pw + lr * 128;
#pragma unroll
            for (int t = 0; t < 2; t++) {
                unsigned int lo = pk2(s[qf][t][0], s[qf][t][1]);
                unsigned int hi = pk2(s[qf][t][2], s[qf][t][3]);
                int byte0 = ((t << 5) + (lg << 3)) ^ swz;
                *(unsigned int*)(base + byte0)     = lo;
                *(unsigned int*)(base + byte0 + 4) = hi;
            }
            pa[qf] = *(const s16x8*)(pw + lr * 128 + ((lg << 4) ^ swz));
        }
        // PV: V from LDS (staged, swizzled): lane needs V[j=lg*8+e][c=16cf+lr]
#pragma unroll
        for (int cf = 0; cf < 8; cf++) {
            s16x8 vb = *(const s16x8*)(vbb + ((16 * cf + lr) << 6) +
                                       ((lg ^ (lr & 3)) << 4));
            oacc[0][cf] = mfma16(pa[0], vb, oacc[0][cf]);
            oacc[1][cf] = mfma16(pa[1], vb, oacc[1][cf]);
        }
        __syncthreads();
        pb ^= 1;
    }
    // write unnormalized partial O + (m,l)
#pragma unroll
    for (int qf = 0; qf < 2; qf++) {
#pragma unroll
        for (int i = 0; i < 4; i++) {
            size_t row = ((size_t)(cz * B_ + b) * N_ + q0 + 16 * qf + lg * 4 + i) * CI_;
#pragma unroll
            for (int cf = 0; cf < 8; cf++)
                OP[row + 16 * cf + lr] = __float2bfloat16(oacc[qf][cf][i]);
        }
        if (lg == 0) {
            size_t mi = ((size_t)(cz * B_ + b) * N_ + q0 + 16 * qf + lr) * 2;
            ML[mi] = m_i[qf];
            ML[mi + 1] = l_i[qf];
        }
    }
}

// ---------------- combine split-KV partials -> O ---------------------------
template <int NC>
__global__ __launch_bounds__(256) void combine(char* ws,
                                               unsigned long long off_part,
                                               unsigned long long off_ml) {
    const __hip_bfloat16* OP = (const __hip_bfloat16*)(ws + off_part);
    const float* ML = (const float*)(ws + off_ml);
    __hip_bfloat16* O = (__hip_bfloat16*)(ws + OFF_O);
    int idx = blockIdx.x * 256 + threadIdx.x;      // B*N*16 threads
    int cg = idx & 15, n = (idx >> 4) & (N_ - 1), b = idx >> 16;
    float mz[NC], lz[NC], M = -1e30f;
#pragma unroll
    for (int z = 0; z < NC; z++) {
        size_t mi = ((size_t)(z * B_ + b) * N_ + n) * 2;
        mz[z] = ML[mi]; lz[z] = ML[mi + 1];
        M = fmaxf(M, mz[z]);
    }
    float Lsum = 0.f, wz[NC];
#pragma unroll
    for (int z = 0; z < NC; z++) { wz[z] = exp2f(mz[z] - M); Lsum += lz[z] * wz[z]; }
    float inv = 1.f / Lsum;
    float o[8] = {};
#pragma unroll
    for (int z = 0; z < NC; z++) {
        s16x8 v = ld8(OP + ((size_t)(z * B_ + b) * N_ + n) * CI_ + cg * 8);
#pragma unroll
        for (int i = 0; i < 8; i++) o[i] += wz[z] * b2f(v[i]);
    }
    s16x8 r;
#pragma unroll
    for (int i = 0; i < 8; i++) {
        __hip_bfloat16 h = __float2bfloat16(o[i] * inv);
        r[i] = *(short*)&h;
    }
    *(s16x8*)(O + ((size_t)b * N_ + n) * CI_ + cg * 8) = r;
}

// ---------------- out projection + bias + residual (single pass over O) ----
// grid (64, B_), block 256; wave covers o = w*16 + f2*64, n-range 64
__global__ __launch_bounds__(256) void gemm_out(const float* x, char* ws, float* y) {
    const __hip_bfloat16* Ob = (const __hip_bfloat16*)(ws + OFF_O);
    const __hip_bfloat16* Wo = (const __hip_bfloat16*)(ws + OFF_WOUT);
    const float* Bout = (const float*)(ws + OFF_BOUT);
    int b = blockIdx.y;
    int w = threadIdx.x >> 6, l = threadIdx.x & 63, lr = l & 15, lg = l >> 4;
    int n0 = blockIdx.x * 64;
    f32x4 acc[4][4] = {};   // [f2 o-tile][nf]
#pragma unroll
    for (int kk = 0; kk < 4; kk++) {
        s16x8 bb[4];
#pragma unroll
        for (int nf = 0; nf < 4; nf++)
            bb[nf] = ld8(Ob + (size_t)(b * N_ + n0 + 16 * nf + lr) * CI_ + kk * 32 + lg * 8);
#pragma unroll
        for (int f2 = 0; f2 < 4; f2++) {
            s16x8 a = ld8(Wo + (size_t)(w * 16 + f2 * 64 + lr) * CI_ + kk * 32 + lg * 8);
#pragma unroll
            for (int nf = 0; nf < 4; nf++)
                acc[f2][nf] = mfma16(a, bb[nf], acc[f2][nf]);
        }
    }
#pragma unroll
    for (int f2 = 0; f2 < 4; f2++) {
#pragma unroll
        for (int i = 0; i < 4; i++) {
            int o = w * 16 + f2 * 64 + lg * 4 + i;
            float bias = Bout[o];
#pragma unroll
            for (int nf = 0; nf < 4; nf++) {
                int n = n0 + 16 * nf + lr;
                size_t idx = (size_t)(b * C_ + o) * N_ + n;
                y[idx] = acc[f2][nf][i] + bias + x[idx];
            }
        }
    }
}

extern "C" void kernel_launch(void* const* d_in, const int* in_sizes, int n_in,
                              void* d_out, int out_size, void* d_ws, size_t ws_size,
                              hipStream_t stream) {
    const float* x  = (const float*)d_in[0];
    const float* wg = (const float*)d_in[1];
    const float* bg = (const float*)d_in[2];
    const float* wt = (const float*)d_in[3];
    const float* bt = (const float*)d_in[4];
    const float* wp = (const float*)d_in[5];
    const float* bp = (const float*)d_in[6];
    const float* wo = (const float*)d_in[7];
    const float* bo = (const float*)d_in[8];
    char* ws = (char*)d_ws;
    float* y = (float*)d_out;

    // split-KV factor, adaptive on workspace size
    unsigned long long need8 = OFF_END + (32ull << 20) + (2ull << 20);
    unsigned long long need4 = OFF_END + (16ull << 20) + (1ull << 20);
    int nchunk;
    unsigned long long off_part, off_ml;
    if (ws_size >= need8) {
        nchunk = 8; off_part = OFF_END; off_ml = OFF_END + (32ull << 20);
    } else if (ws_size >= need4) {
        nchunk = 4; off_part = OFF_END; off_ml = OFF_END + (16ull << 20);
    } else {
        nchunk = 2; off_part = OFF_XT; off_ml = OFF_END;
    }

    prep_weights<<<256, 256, 0, stream>>>(wg, bg, wt, bt, wp, bp, wo, bo, ws);
    transpose_x<<<dim3(128, 8, 4), 256, 0, stream>>>(x, ws);
    proj<<<dim3(128, 4), 256, 0, stream>>>(ws);
    flash4<<<dim3(128 * nchunk), 256, 0, stream>>>(ws, nchunk, off_part, off_ml);
    if (nchunk == 8)      combine<8><<<1024, 256, 0, stream>>>(ws, off_part, off_ml);
    else if (nchunk == 4) combine<4><<<1024, 256, 0, stream>>>(ws, off_part, off_ml);
    else                  combine<2><<<1024, 256, 0, stream>>>(ws, off_part, off_ml);
    gemm_out<<<dim3(64, 4), 256, 0, stream>>>(x, ws, y);
}

// Round 5
// 107.661 us; speedup vs baseline: 3.8663x; 1.4457x over previous
//
#include <hip/hip_runtime.h>
#include <hip/hip_bf16.h>

// NonLocal block == flash attention (4 heads, N=4096, D=128) + 1x1-conv GEMMs.
// Round 5: fix R4 spill (launch_bounds 256,3); one-shot max (tile-0 init, no
// per-tile rescale); deferred l-sum; per-qf pbuf; setprio around MFMA.

typedef float f32x4 __attribute__((ext_vector_type(4)));
typedef short s16x8 __attribute__((ext_vector_type(8)));

#define B_  4
#define C_  256
#define CI_ 128
#define N_  4096

// workspace layout (bytes)
#define OFF_XT   0ull                    // bf16 [B][N][C]   8 MB
#define OFF_Q    (8ull  << 20)           // bf16 [B][N][CI]  4 MB (theta^T, scaled)
#define OFF_K    (12ull << 20)           // bf16 [B][N][CI]  4 MB (phi^T)
#define OFF_G    (16ull << 20)           // bf16 [B][CI][N]  4 MB (g, V^T layout)
#define OFF_O    (20ull << 20)           // bf16 [B][N][CI]  4 MB (combined attn out)
#define OFF_WQK  (24ull << 20)
#define OFF_WG   (OFF_WQK + 131072)
#define OFF_WOUT (OFF_WG  + 65536)
#define OFF_BQK  (OFF_WOUT + 65536)
#define OFF_BG   (OFF_BQK + 1024)
#define OFF_BOUT (OFF_BG  + 512)
#define OFF_END  (OFF_BOUT + 1024)       // = 25430528

__device__ inline f32x4 mfma16(s16x8 a, s16x8 b, f32x4 c) {
    return __builtin_amdgcn_mfma_f32_16x16x32_bf16(a, b, c, 0, 0, 0);
}
__device__ inline s16x8 ld8(const __hip_bfloat16* p) { return *(const s16x8*)p; }
__device__ inline float b2f(short u) {
    return __uint_as_float(((unsigned int)(unsigned short)u) << 16);
}
__device__ inline unsigned int pk2(float a, float b) {
    __hip_bfloat162 h;
    h.x = __float2bfloat16(a); h.y = __float2bfloat16(b);
    return *(unsigned int*)&h;
}
__device__ inline void gload_lds16(const void* g, void* l) {
    __builtin_amdgcn_global_load_lds(
        (const __attribute__((address_space(1))) unsigned int*)g,
        (__attribute__((address_space(3))) unsigned int*)l, 16, 0, 0);
}
__device__ inline float fexp2(float x) { return __builtin_amdgcn_exp2f(x); }

// ---------------- weight prep: fp32 -> bf16; fold log2e/sqrt(Ci) into theta
__global__ void prep_weights(const float* wg, const float* bg,
                             const float* wt, const float* bt,
                             const float* wp, const float* bp,
                             const float* wo, const float* bo, char* ws) {
    __hip_bfloat16* Wqk  = (__hip_bfloat16*)(ws + OFF_WQK);
    __hip_bfloat16* Wg   = (__hip_bfloat16*)(ws + OFF_WG);
    __hip_bfloat16* Wout = (__hip_bfloat16*)(ws + OFF_WOUT);
    float* Bqk  = (float*)(ws + OFF_BQK);
    float* Bg   = (float*)(ws + OFF_BG);
    float* Bout = (float*)(ws + OFF_BOUT);
    const float rs = 0.08838834764831845f * 1.4426950408889634f;  // 1/sqrt(128)*log2(e)
    int idx = blockIdx.x * 256 + threadIdx.x;
    if (idx < 65536) {
        int r = idx >> 8, c = idx & 255;
        float v = (r < 128) ? wt[r * 256 + c] * rs : wp[(r - 128) * 256 + c];
        Wqk[idx] = __float2bfloat16(v);
    }
    if (idx < 32768) {
        Wg[idx]   = __float2bfloat16(wg[idx]);
        Wout[idx] = __float2bfloat16(wo[idx]);
    }
    if (idx < 256) { Bqk[idx] = (idx < 128) ? bt[idx] * rs : bp[idx - 128]; Bout[idx] = bo[idx]; }
    if (idx < 128) Bg[idx] = bg[idx];
}

// ---------------- x [B][C][N] f32 -> XT [B][N][C] bf16 -------------------
__global__ __launch_bounds__(256) void transpose_x(const float* x, char* ws) {
    __shared__ float tile[32][33];
    __hip_bfloat16* XT = (__hip_bfloat16*)(ws + OFF_XT);
    int b = blockIdx.z;
    int n0 = blockIdx.x * 32, c0 = blockIdx.y * 32;
    int tx = threadIdx.x & 31, ty = threadIdx.x >> 5;
#pragma unroll
    for (int r = 0; r < 4; r++)
        tile[ty + 8 * r][tx] = x[(size_t)(b * C_ + c0 + ty + 8 * r) * N_ + n0 + tx];
    __syncthreads();
#pragma unroll
    for (int r = 0; r < 4; r++)
        XT[(size_t)(b * N_ + n0 + ty + 8 * r) * C_ + c0 + tx] =
            __float2bfloat16(tile[tx][ty + 8 * r]);
}

// ---------------- fused projection: Q, K, G from XT in one pass ------------
__global__ __launch_bounds__(256) void proj(char* ws) {
    const __hip_bfloat16* XT  = (const __hip_bfloat16*)(ws + OFF_XT);
    const __hip_bfloat16* Wqk = (const __hip_bfloat16*)(ws + OFF_WQK);
    const __hip_bfloat16* Wg  = (const __hip_bfloat16*)(ws + OFF_WG);
    const float* Bqk = (const float*)(ws + OFF_BQK);
    const float* Bg  = (const float*)(ws + OFF_BG);
    __hip_bfloat16* Q  = (__hip_bfloat16*)(ws + OFF_Q);
    __hip_bfloat16* Kb = (__hip_bfloat16*)(ws + OFF_K);
    __hip_bfloat16* G  = (__hip_bfloat16*)(ws + OFF_G);

    __shared__ char at[32 * 512];   // [32 n][256 c] bf16, 16B slots XOR-swizzled

    int b = blockIdx.y, n0 = blockIdx.x * 32;
    int w = threadIdx.x >> 6, l = threadIdx.x & 63, lr = l & 15, lg = l >> 4;

    const char* xbase = (const char*)(XT + ((size_t)b * N_ + n0) * C_);
#pragma unroll
    for (int p = 0; p < 4; p++) {
        int row = p * 8 + w * 2 + (l >> 5);
        int slot = l & 31;
        const char* src = xbase + row * 512 + ((slot ^ (row & 7)) << 4);
        gload_lds16(src, &at[(p * 8 + w * 2) * 512]);
    }
    __syncthreads();

    f32x4 acc[4][2] = {};    // QK path: [of][nf]
    f32x4 accg[2][2] = {};   // G  path: [og][nf]
    int o0q = w * 64, o0g = w * 32;
#pragma unroll
    for (int kk = 0; kk < 8; kk++) {
        s16x8 a[2];
#pragma unroll
        for (int nf = 0; nf < 2; nf++) {
            int row = nf * 16 + lr;
            int s = (4 * kk + lg) ^ (row & 7);
            a[nf] = *(const s16x8*)(&at[row * 512 + s * 16]);
        }
#pragma unroll
        for (int of = 0; of < 4; of++) {
            s16x8 bb = ld8(Wqk + (size_t)(o0q + 16 * of + lr) * C_ + kk * 32 + lg * 8);
            acc[of][0] = mfma16(a[0], bb, acc[of][0]);
            acc[of][1] = mfma16(a[1], bb, acc[of][1]);
        }
#pragma unroll
        for (int og = 0; og < 2; og++) {
            s16x8 ag = ld8(Wg + (size_t)(o0g + 16 * og + lr) * C_ + kk * 32 + lg * 8);
            accg[og][0] = mfma16(ag, a[0], accg[og][0]);
            accg[og][1] = mfma16(ag, a[1], accg[og][1]);
        }
    }
#pragma unroll
    for (int of = 0; of < 4; of++) {
        int o = o0q + 16 * of + lr;
        float bias = Bqk[o];
#pragma unroll
        for (int nf = 0; nf < 2; nf++) {
#pragma unroll
            for (int i = 0; i < 4; i++) {
                int n = n0 + 16 * nf + lg * 4 + i;
                float v = acc[of][nf][i] + bias;
                if (o < 128) Q [(size_t)(b * N_ + n) * CI_ + o]         = __float2bfloat16(v);
                else         Kb[(size_t)(b * N_ + n) * CI_ + (o - 128)] = __float2bfloat16(v);
            }
        }
    }
#pragma unroll
    for (int og = 0; og < 2; og++) {
#pragma unroll
        for (int i = 0; i < 4; i++) {
            int o = o0g + 16 * og + lg * 4 + i;
            float bias = Bg[o];
#pragma unroll
            for (int nf = 0; nf < 2; nf++) {
                int n = n0 + 16 * nf + lr;
                G[(size_t)(b * CI_ + o) * N_ + n] = __float2bfloat16(accg[og][nf][i] + bias);
            }
        }
    }
}

// ---------------- flash v5: K+V LDS dbuf; one-shot max; deferred l-sum -----
// grid: 128*nchunk blocks of 256 (4 waves); wave = 32 q-rows, KVBLK=32.
__global__ __launch_bounds__(256, 3) void flash5(char* ws, int nchunk,
                                                 unsigned long long off_part,
                                                 unsigned long long off_ml) {
    const __hip_bfloat16* Q  = (const __hip_bfloat16*)(ws + OFF_Q);
    const __hip_bfloat16* Kb = (const __hip_bfloat16*)(ws + OFF_K);
    const __hip_bfloat16* G  = (const __hip_bfloat16*)(ws + OFF_G);
    __hip_bfloat16* OP = (__hip_bfloat16*)(ws + off_part);
    float* ML = (float*)(ws + off_ml);

    __shared__ char kbuf[2][32 * 256];   // K tile [32 j][256 B], swizzled slots
    __shared__ char vbuf[2][128 * 64];   // V tile [128 c][64 B], swizzled slots
    __shared__ char pbuf[4][2][2048];    // per-wave, per-qf P staging

    int L = blockIdx.x;
    int pair, qt, b, cz;
    if (nchunk == 8)      { pair = L & 31; qt = L >> 5; b = pair >> 3; cz = pair & 7; }
    else if (nchunk == 4) { pair = L & 15; qt = L >> 4; b = pair >> 2; cz = pair & 3; }
    else                  { pair = L & 7;  qt = L >> 3; b = pair >> 1; cz = pair & 1; }
    int CH = N_ / nchunk;
    int jb = cz * CH, je = jb + CH;

    int w = threadIdx.x >> 6, l = threadIdx.x & 63, lr = l & 15, lg = l >> 4;
    int q0 = qt * 128 + w * 32;
    int swz = (lr & 7) << 4;
    char* pw = &pbuf[w][0][0];

    auto STAGE = [&](int pb_, int j0_) {
#pragma unroll
        for (int i = 0; i < 2; i++) {
            int row = w * 8 + i * 4 + (l >> 4);
            int bcol = ((l & 15) << 4) ^ ((row & 7) << 4);
            const char* src = (const char*)Kb + (((size_t)b * N_ + j0_ + row) << 8) + bcol;
            gload_lds16(src, &kbuf[pb_][(w * 8 + i * 4) * 256]);
        }
#pragma unroll
        for (int i = 0; i < 2; i++) {
            int c = w * 32 + i * 16 + (l >> 2);
            int joct = l & 3;
            const char* src = (const char*)G + ((((size_t)b * CI_ + c) * N_ + j0_) << 1)
                              + ((joct ^ (c & 3)) << 4);
            gload_lds16(src, &vbuf[pb_][(w * 32 + i * 16) * 64]);
        }
    };

    // Q as B-operand: lane holds Q[k = kk*32+lg*8+e][col q = q0+16qf+lr]
    s16x8 qa[2][4];
#pragma unroll
    for (int qf = 0; qf < 2; qf++) {
        const __hip_bfloat16* qrow = Q + ((size_t)b * N_ + q0 + 16 * qf + lr) * CI_ + lg * 8;
#pragma unroll
        for (int kk = 0; kk < 4; kk++) qa[qf][kk] = ld8(qrow + kk * 32);
    }

    f32x4 oacc[2][8] = {};
    float m_i[2], lsum[2] = {0.f, 0.f};

    STAGE(0, jb);
    __syncthreads();
    int pb = 0;

    for (int j0 = jb; j0 < je; j0 += 32) {
        if (j0 + 32 < je) STAGE(pb ^ 1, j0 + 32);
        const char* kb = kbuf[pb];
        const char* vbb = vbuf[pb];
        // S^T = K Q  (swapped: lane owns 16 j of one q per qf)
        f32x4 s[2][2] = {};
        __builtin_amdgcn_s_setprio(1);
#pragma unroll
        for (int kk = 0; kk < 4; kk++) {
            int bc = ((kk << 6) + (lg << 4)) ^ swz;
            s16x8 kf0 = *(const s16x8*)(kb + lr * 256 + bc);
            s16x8 kf1 = *(const s16x8*)(kb + (16 + lr) * 256 + bc);
            s[0][0] = mfma16(kf0, qa[0][kk], s[0][0]);
            s[1][0] = mfma16(kf0, qa[1][kk], s[1][0]);
            s[0][1] = mfma16(kf1, qa[0][kk], s[0][1]);
            s[1][1] = mfma16(kf1, qa[1][kk], s[1][1]);
        }
        __builtin_amdgcn_s_setprio(0);
        // one-shot max init from first tile (per q row = lane lr, per qf)
        if (j0 == jb) {
#pragma unroll
            for (int qf = 0; qf < 2; qf++) {
                f32x4 m4;
                m4[0] = fmaxf(s[qf][0][0], s[qf][1][0]);
                m4[1] = fmaxf(s[qf][0][1], s[qf][1][1]);
                m4[2] = fmaxf(s[qf][0][2], s[qf][1][2]);
                m4[3] = fmaxf(s[qf][0][3], s[qf][1][3]);
                float tm = fmaxf(fmaxf(m4[0], m4[1]), fmaxf(m4[2], m4[3]));
                tm = fmaxf(tm, __shfl_xor(tm, 16));
                tm = fmaxf(tm, __shfl_xor(tm, 32));
                m_i[qf] = tm;
            }
        }
        // exp2 + lane-local l accumulation + pack P (both qf, no serialization)
#pragma unroll
        for (int qf = 0; qf < 2; qf++) {
            float mref = m_i[qf];
            f32x4 sum4 = {};
#pragma unroll
            for (int t = 0; t < 2; t++) {
#pragma unroll
                for (int i = 0; i < 4; i++) s[qf][t][i] = fexp2(s[qf][t][i] - mref);
                sum4 += s[qf][t];
            }
            lsum[qf] += (sum4[0] + sum4[1]) + (sum4[2] + sum4[3]);
            char* base = pw + qf * 2048 + lr * 128;
#pragma unroll
            for (int t = 0; t < 2; t++) {
                unsigned int lo = pk2(s[qf][t][0], s[qf][t][1]);
                unsigned int hi = pk2(s[qf][t][2], s[qf][t][3]);
                int byte0 = ((t << 5) + (lg << 3)) ^ swz;
                *(unsigned int*)(base + byte0)     = lo;
                *(unsigned int*)(base + byte0 + 4) = hi;
            }
        }
        s16x8 pa0 = *(const s16x8*)(pw + lr * 128 + ((lg << 4) ^ swz));
        s16x8 pa1 = *(const s16x8*)(pw + 2048 + lr * 128 + ((lg << 4) ^ swz));
        // PV: V from LDS: lane needs V[j=lg*8+e][c=16cf+lr]
        __builtin_amdgcn_s_setprio(1);
#pragma unroll
        for (int cf = 0; cf < 8; cf++) {
            s16x8 vb = *(const s16x8*)(vbb + ((16 * cf + lr) << 6) +
                                       ((lg ^ (lr & 3)) << 4));
            oacc[0][cf] = mfma16(pa0, vb, oacc[0][cf]);
            oacc[1][cf] = mfma16(pa1, vb, oacc[1][cf]);
        }
        __builtin_amdgcn_s_setprio(0);
        __syncthreads();
        pb ^= 1;
    }
    // finalize l: 2 shuffles once per chunk
    float l_i[2];
#pragma unroll
    for (int qf = 0; qf < 2; qf++) {
        float rs = lsum[qf];
        rs += __shfl_xor(rs, 16);
        rs += __shfl_xor(rs, 32);
        l_i[qf] = rs;
    }
    // write unnormalized partial O + (m,l)
#pragma unroll
    for (int qf = 0; qf < 2; qf++) {
#pragma unroll
        for (int i = 0; i < 4; i++) {
            size_t row = ((size_t)(cz * B_ + b) * N_ + q0 + 16 * qf + lg * 4 + i) * CI_;
#pragma unroll
            for (int cf = 0; cf < 8; cf++)
                OP[row + 16 * cf + lr] = __float2bfloat16(oacc[qf][cf][i]);
        }
        if (lg == 0) {
            size_t mi = ((size_t)(cz * B_ + b) * N_ + q0 + 16 * qf + lr) * 2;
            ML[mi] = m_i[qf];
            ML[mi + 1] = l_i[qf];
        }
    }
}

// ---------------- combine split-KV partials -> O ---------------------------
template <int NC>
__global__ __launch_bounds__(256) void combine(char* ws,
                                               unsigned long long off_part,
                                               unsigned long long off_ml) {
    const __hip_bfloat16* OP = (const __hip_bfloat16*)(ws + off_part);
    const float* ML = (const float*)(ws + off_ml);
    __hip_bfloat16* O = (__hip_bfloat16*)(ws + OFF_O);
    int idx = blockIdx.x * 256 + threadIdx.x;      // B*N*16 threads
    int cg = idx & 15, n = (idx >> 4) & (N_ - 1), b = idx >> 16;
    float mz[NC], lz[NC], M = -1e30f;
#pragma unroll
    for (int z = 0; z < NC; z++) {
        size_t mi = ((size_t)(z * B_ + b) * N_ + n) * 2;
        mz[z] = ML[mi]; lz[z] = ML[mi + 1];
        M = fmaxf(M, mz[z]);
    }
    float Lsum = 0.f, wz[NC];
#pragma unroll
    for (int z = 0; z < NC; z++) { wz[z] = exp2f(mz[z] - M); Lsum += lz[z] * wz[z]; }
    float inv = 1.f / Lsum;
    float o[8] = {};
#pragma unroll
    for (int z = 0; z < NC; z++) {
        s16x8 v = ld8(OP + ((size_t)(z * B_ + b) * N_ + n) * CI_ + cg * 8);
#pragma unroll
        for (int i = 0; i < 8; i++) o[i] += wz[z] * b2f(v[i]);
    }
    s16x8 r;
#pragma unroll
    for (int i = 0; i < 8; i++) {
        __hip_bfloat16 h = __float2bfloat16(o[i] * inv);
        r[i] = *(short*)&h;
    }
    *(s16x8*)(O + ((size_t)b * N_ + n) * CI_ + cg * 8) = r;
}

// ---------------- out projection + bias + residual (single pass over O) ----
__global__ __launch_bounds__(256) void gemm_out(const float* x, char* ws, float* y) {
    const __hip_bfloat16* Ob = (const __hip_bfloat16*)(ws + OFF_O);
    const __hip_bfloat16* Wo = (const __hip_bfloat16*)(ws + OFF_WOUT);
    const float* Bout = (const float*)(ws + OFF_BOUT);
    int b = blockIdx.y;
    int w = threadIdx.x >> 6, l = threadIdx.x & 63, lr = l & 15, lg = l >> 4;
    int n0 = blockIdx.x * 64;
    f32x4 acc[4][4] = {};   // [f2 o-tile][nf]
#pragma unroll
    for (int kk = 0; kk < 4; kk++) {
        s16x8 bb[4];
#pragma unroll
        for (int nf = 0; nf < 4; nf++)
            bb[nf] = ld8(Ob + (size_t)(b * N_ + n0 + 16 * nf + lr) * CI_ + kk * 32 + lg * 8);
#pragma unroll
        for (int f2 = 0; f2 < 4; f2++) {
            s16x8 a = ld8(Wo + (size_t)(w * 16 + f2 * 64 + lr) * CI_ + kk * 32 + lg * 8);
#pragma unroll
            for (int nf = 0; nf < 4; nf++)
                acc[f2][nf] = mfma16(a, bb[nf], acc[f2][nf]);
        }
    }
#pragma unroll
    for (int f2 = 0; f2 < 4; f2++) {
#pragma unroll
        for (int i = 0; i < 4; i++) {
            int o = w * 16 + f2 * 64 + lg * 4 + i;
            float bias = Bout[o];
#pragma unroll
            for (int nf = 0; nf < 4; nf++) {
                int n = n0 + 16 * nf + lr;
                size_t idx = (size_t)(b * C_ + o) * N_ + n;
                y[idx] = acc[f2][nf][i] + bias + x[idx];
            }
        }
    }
}

extern "C" void kernel_launch(void* const* d_in, const int* in_sizes, int n_in,
                              void* d_out, int out_size, void* d_ws, size_t ws_size,
                              hipStream_t stream) {
    const float* x  = (const float*)d_in[0];
    const float* wg = (const float*)d_in[1];
    const float* bg = (const float*)d_in[2];
    const float* wt = (const float*)d_in[3];
    const float* bt = (const float*)d_in[4];
    const float* wp = (const float*)d_in[5];
    const float* bp = (const float*)d_in[6];
    const float* wo = (const float*)d_in[7];
    const float* bo = (const float*)d_in[8];
    char* ws = (char*)d_ws;
    float* y = (float*)d_out;

    unsigned long long need8 = OFF_END + (32ull << 20) + (2ull << 20);
    unsigned long long need4 = OFF_END + (16ull << 20) + (1ull << 20);
    int nchunk;
    unsigned long long off_part, off_ml;
    if (ws_size >= need8) {
        nchunk = 8; off_part = OFF_END; off_ml = OFF_END + (32ull << 20);
    } else if (ws_size >= need4) {
        nchunk = 4; off_part = OFF_END; off_ml = OFF_END + (16ull << 20);
    } else {
        nchunk = 2; off_part = OFF_XT; off_ml = OFF_END;
    }

    prep_weights<<<256, 256, 0, stream>>>(wg, bg, wt, bt, wp, bp, wo, bo, ws);
    transpose_x<<<dim3(128, 8, 4), 256, 0, stream>>>(x, ws);
    proj<<<dim3(128, 4), 256, 0, stream>>>(ws);
    flash5<<<dim3(128 * nchunk), 256, 0, stream>>>(ws, nchunk, off_part, off_ml);
    if (nchunk == 8)      combine<8><<<1024, 256, 0, stream>>>(ws, off_part, off_ml);
    else if (nchunk == 4) combine<4><<<1024, 256, 0, stream>>>(ws, off_part, off_ml);
    else                  combine<2><<<1024, 256, 0, stream>>>(ws, off_part, off_ml);
    gemm_out<<<dim3(64, 4), 256, 0, stream>>>(x, ws, y);
}

// Round 6
// 101.701 us; speedup vs baseline: 4.0929x; 1.0586x over previous
//
#include <hip/hip_runtime.h>
#include <hip/hip_bf16.h>

// NonLocal block == flash attention (4 heads, N=4096, D=128) + 1x1-conv GEMMs.
// Round 6: grid sized to exactly fill residency (nchunk=6 -> 768 blocks at
// 3 blocks/CU, no ragged tail). Structure otherwise identical to R5.

typedef float f32x4 __attribute__((ext_vector_type(4)));
typedef short s16x8 __attribute__((ext_vector_type(8)));

#define B_  4
#define C_  256
#define CI_ 128
#define N_  4096

// workspace layout (bytes)
#define OFF_XT   0ull                    // bf16 [B][N][C]   8 MB
#define OFF_Q    (8ull  << 20)           // bf16 [B][N][CI]  4 MB (theta^T, scaled)
#define OFF_K    (12ull << 20)           // bf16 [B][N][CI]  4 MB (phi^T)
#define OFF_G    (16ull << 20)           // bf16 [B][CI][N]  4 MB (g, V^T layout)
#define OFF_O    (20ull << 20)           // bf16 [B][N][CI]  4 MB (combined attn out)
#define OFF_WQK  (24ull << 20)
#define OFF_WG   (OFF_WQK + 131072)
#define OFF_WOUT (OFF_WG  + 65536)
#define OFF_BQK  (OFF_WOUT + 65536)
#define OFF_BG   (OFF_BQK + 1024)
#define OFF_BOUT (OFF_BG  + 512)
#define OFF_END  (OFF_BOUT + 1024)       // = 25430528

__device__ inline f32x4 mfma16(s16x8 a, s16x8 b, f32x4 c) {
    return __builtin_amdgcn_mfma_f32_16x16x32_bf16(a, b, c, 0, 0, 0);
}
__device__ inline s16x8 ld8(const __hip_bfloat16* p) { return *(const s16x8*)p; }
__device__ inline float b2f(short u) {
    return __uint_as_float(((unsigned int)(unsigned short)u) << 16);
}
__device__ inline unsigned int pk2(float a, float b) {
    __hip_bfloat162 h;
    h.x = __float2bfloat16(a); h.y = __float2bfloat16(b);
    return *(unsigned int*)&h;
}
__device__ inline void gload_lds16(const void* g, void* l) {
    __builtin_amdgcn_global_load_lds(
        (const __attribute__((address_space(1))) unsigned int*)g,
        (__attribute__((address_space(3))) unsigned int*)l, 16, 0, 0);
}
__device__ inline float fexp2(float x) { return __builtin_amdgcn_exp2f(x); }

// ---------------- weight prep: fp32 -> bf16; fold log2e/sqrt(Ci) into theta
__global__ void prep_weights(const float* wg, const float* bg,
                             const float* wt, const float* bt,
                             const float* wp, const float* bp,
                             const float* wo, const float* bo, char* ws) {
    __hip_bfloat16* Wqk  = (__hip_bfloat16*)(ws + OFF_WQK);
    __hip_bfloat16* Wg   = (__hip_bfloat16*)(ws + OFF_WG);
    __hip_bfloat16* Wout = (__hip_bfloat16*)(ws + OFF_WOUT);
    float* Bqk  = (float*)(ws + OFF_BQK);
    float* Bg   = (float*)(ws + OFF_BG);
    float* Bout = (float*)(ws + OFF_BOUT);
    const float rs = 0.08838834764831845f * 1.4426950408889634f;  // 1/sqrt(128)*log2(e)
    int idx = blockIdx.x * 256 + threadIdx.x;
    if (idx < 65536) {
        int r = idx >> 8, c = idx & 255;
        float v = (r < 128) ? wt[r * 256 + c] * rs : wp[(r - 128) * 256 + c];
        Wqk[idx] = __float2bfloat16(v);
    }
    if (idx < 32768) {
        Wg[idx]   = __float2bfloat16(wg[idx]);
        Wout[idx] = __float2bfloat16(wo[idx]);
    }
    if (idx < 256) { Bqk[idx] = (idx < 128) ? bt[idx] * rs : bp[idx - 128]; Bout[idx] = bo[idx]; }
    if (idx < 128) Bg[idx] = bg[idx];
}

// ---------------- x [B][C][N] f32 -> XT [B][N][C] bf16 -------------------
__global__ __launch_bounds__(256) void transpose_x(const float* x, char* ws) {
    __shared__ float tile[32][33];
    __hip_bfloat16* XT = (__hip_bfloat16*)(ws + OFF_XT);
    int b = blockIdx.z;
    int n0 = blockIdx.x * 32, c0 = blockIdx.y * 32;
    int tx = threadIdx.x & 31, ty = threadIdx.x >> 5;
#pragma unroll
    for (int r = 0; r < 4; r++)
        tile[ty + 8 * r][tx] = x[(size_t)(b * C_ + c0 + ty + 8 * r) * N_ + n0 + tx];
    __syncthreads();
#pragma unroll
    for (int r = 0; r < 4; r++)
        XT[(size_t)(b * N_ + n0 + ty + 8 * r) * C_ + c0 + tx] =
            __float2bfloat16(tile[tx][ty + 8 * r]);
}

// ---------------- fused projection: Q, K, G from XT in one pass ------------
__global__ __launch_bounds__(256) void proj(char* ws) {
    const __hip_bfloat16* XT  = (const __hip_bfloat16*)(ws + OFF_XT);
    const __hip_bfloat16* Wqk = (const __hip_bfloat16*)(ws + OFF_WQK);
    const __hip_bfloat16* Wg  = (const __hip_bfloat16*)(ws + OFF_WG);
    const float* Bqk = (const float*)(ws + OFF_BQK);
    const float* Bg  = (const float*)(ws + OFF_BG);
    __hip_bfloat16* Q  = (__hip_bfloat16*)(ws + OFF_Q);
    __hip_bfloat16* Kb = (__hip_bfloat16*)(ws + OFF_K);
    __hip_bfloat16* G  = (__hip_bfloat16*)(ws + OFF_G);

    __shared__ char at[32 * 512];   // [32 n][256 c] bf16, 16B slots XOR-swizzled

    int b = blockIdx.y, n0 = blockIdx.x * 32;
    int w = threadIdx.x >> 6, l = threadIdx.x & 63, lr = l & 15, lg = l >> 4;

    const char* xbase = (const char*)(XT + ((size_t)b * N_ + n0) * C_);
#pragma unroll
    for (int p = 0; p < 4; p++) {
        int row = p * 8 + w * 2 + (l >> 5);
        int slot = l & 31;
        const char* src = xbase + row * 512 + ((slot ^ (row & 7)) << 4);
        gload_lds16(src, &at[(p * 8 + w * 2) * 512]);
    }
    __syncthreads();

    f32x4 acc[4][2] = {};    // QK path: [of][nf]
    f32x4 accg[2][2] = {};   // G  path: [og][nf]
    int o0q = w * 64, o0g = w * 32;
#pragma unroll
    for (int kk = 0; kk < 8; kk++) {
        s16x8 a[2];
#pragma unroll
        for (int nf = 0; nf < 2; nf++) {
            int row = nf * 16 + lr;
            int s = (4 * kk + lg) ^ (row & 7);
            a[nf] = *(const s16x8*)(&at[row * 512 + s * 16]);
        }
#pragma unroll
        for (int of = 0; of < 4; of++) {
            s16x8 bb = ld8(Wqk + (size_t)(o0q + 16 * of + lr) * C_ + kk * 32 + lg * 8);
            acc[of][0] = mfma16(a[0], bb, acc[of][0]);
            acc[of][1] = mfma16(a[1], bb, acc[of][1]);
        }
#pragma unroll
        for (int og = 0; og < 2; og++) {
            s16x8 ag = ld8(Wg + (size_t)(o0g + 16 * og + lr) * C_ + kk * 32 + lg * 8);
            accg[og][0] = mfma16(ag, a[0], accg[og][0]);
            accg[og][1] = mfma16(ag, a[1], accg[og][1]);
        }
    }
#pragma unroll
    for (int of = 0; of < 4; of++) {
        int o = o0q + 16 * of + lr;
        float bias = Bqk[o];
#pragma unroll
        for (int nf = 0; nf < 2; nf++) {
#pragma unroll
            for (int i = 0; i < 4; i++) {
                int n = n0 + 16 * nf + lg * 4 + i;
                float v = acc[of][nf][i] + bias;
                if (o < 128) Q [(size_t)(b * N_ + n) * CI_ + o]         = __float2bfloat16(v);
                else         Kb[(size_t)(b * N_ + n) * CI_ + (o - 128)] = __float2bfloat16(v);
            }
        }
    }
#pragma unroll
    for (int og = 0; og < 2; og++) {
#pragma unroll
        for (int i = 0; i < 4; i++) {
            int o = o0g + 16 * og + lg * 4 + i;
            float bias = Bg[o];
#pragma unroll
            for (int nf = 0; nf < 2; nf++) {
                int n = n0 + 16 * nf + lr;
                G[(size_t)(b * CI_ + o) * N_ + n] = __float2bfloat16(accg[og][nf][i] + bias);
            }
        }
    }
}

// ---------------- flash v6: K+V LDS dbuf; one-shot max; no-tail grid -------
// grid: 32 qt * B_ * nchunk blocks of 256 (4 waves); wave = 32 q-rows, KVBLK=32.
// Chunk boundaries are multiples of 32 tiles; sizes differ by <=1 tile.
__global__ __launch_bounds__(256, 3) void flash6(char* ws, int nchunk,
                                                 unsigned long long off_part,
                                                 unsigned long long off_ml) {
    const __hip_bfloat16* Q  = (const __hip_bfloat16*)(ws + OFF_Q);
    const __hip_bfloat16* Kb = (const __hip_bfloat16*)(ws + OFF_K);
    const __hip_bfloat16* G  = (const __hip_bfloat16*)(ws + OFF_G);
    __hip_bfloat16* OP = (__hip_bfloat16*)(ws + off_part);
    float* ML = (float*)(ws + off_ml);

    __shared__ char kbuf[2][32 * 256];   // K tile [32 j][256 B], swizzled slots
    __shared__ char vbuf[2][128 * 64];   // V tile [128 c][64 B], swizzled slots
    __shared__ char pbuf[4][2][2048];    // per-wave, per-qf P staging

    int L = blockIdx.x;
    int npairs = B_ * nchunk;
    int pair = L % npairs, qt = L / npairs;
    int b = pair / nchunk, cz = pair % nchunk;
    // chunk boundaries in 32-j tiles: 128 tiles split as evenly as possible
    int per = 128 / nchunk, rem = 128 % nchunk;
    int jb_t = per * cz + (cz < rem ? cz : rem);
    int sz_t = per + (cz < rem ? 1 : 0);
    int jb = jb_t << 5, je = jb + (sz_t << 5);

    int w = threadIdx.x >> 6, l = threadIdx.x & 63, lr = l & 15, lg = l >> 4;
    int q0 = qt * 128 + w * 32;
    int swz = (lr & 7) << 4;
    char* pw = &pbuf[w][0][0];

    auto STAGE = [&](int pb_, int j0_) {
#pragma unroll
        for (int i = 0; i < 2; i++) {
            int row = w * 8 + i * 4 + (l >> 4);
            int bcol = ((l & 15) << 4) ^ ((row & 7) << 4);
            const char* src = (const char*)Kb + (((size_t)b * N_ + j0_ + row) << 8) + bcol;
            gload_lds16(src, &kbuf[pb_][(w * 8 + i * 4) * 256]);
        }
#pragma unroll
        for (int i = 0; i < 2; i++) {
            int c = w * 32 + i * 16 + (l >> 2);
            int joct = l & 3;
            const char* src = (const char*)G + ((((size_t)b * CI_ + c) * N_ + j0_) << 1)
                              + ((joct ^ (c & 3)) << 4);
            gload_lds16(src, &vbuf[pb_][(w * 32 + i * 16) * 64]);
        }
    };

    // Q as B-operand: lane holds Q[k = kk*32+lg*8+e][col q = q0+16qf+lr]
    s16x8 qa[2][4];
#pragma unroll
    for (int qf = 0; qf < 2; qf++) {
        const __hip_bfloat16* qrow = Q + ((size_t)b * N_ + q0 + 16 * qf + lr) * CI_ + lg * 8;
#pragma unroll
        for (int kk = 0; kk < 4; kk++) qa[qf][kk] = ld8(qrow + kk * 32);
    }

    f32x4 oacc[2][8] = {};
    float m_i[2], lsum[2] = {0.f, 0.f};

    STAGE(0, jb);
    __syncthreads();
    int pb = 0;

    for (int j0 = jb; j0 < je; j0 += 32) {
        if (j0 + 32 < je) STAGE(pb ^ 1, j0 + 32);
        const char* kb = kbuf[pb];
        const char* vbb = vbuf[pb];
        // S^T = K Q  (swapped: lane owns 16 j of one q per qf)
        f32x4 s[2][2] = {};
        __builtin_amdgcn_s_setprio(1);
#pragma unroll
        for (int kk = 0; kk < 4; kk++) {
            int bc = ((kk << 6) + (lg << 4)) ^ swz;
            s16x8 kf0 = *(const s16x8*)(kb + lr * 256 + bc);
            s16x8 kf1 = *(const s16x8*)(kb + (16 + lr) * 256 + bc);
            s[0][0] = mfma16(kf0, qa[0][kk], s[0][0]);
            s[1][0] = mfma16(kf0, qa[1][kk], s[1][0]);
            s[0][1] = mfma16(kf1, qa[0][kk], s[0][1]);
            s[1][1] = mfma16(kf1, qa[1][kk], s[1][1]);
        }
        __builtin_amdgcn_s_setprio(0);
        // one-shot max init from first tile (per q row = lane lr, per qf)
        if (j0 == jb) {
#pragma unroll
            for (int qf = 0; qf < 2; qf++) {
                f32x4 m4;
                m4[0] = fmaxf(s[qf][0][0], s[qf][1][0]);
                m4[1] = fmaxf(s[qf][0][1], s[qf][1][1]);
                m4[2] = fmaxf(s[qf][0][2], s[qf][1][2]);
                m4[3] = fmaxf(s[qf][0][3], s[qf][1][3]);
                float tm = fmaxf(fmaxf(m4[0], m4[1]), fmaxf(m4[2], m4[3]));
                tm = fmaxf(tm, __shfl_xor(tm, 16));
                tm = fmaxf(tm, __shfl_xor(tm, 32));
                m_i[qf] = tm;
            }
        }
        // exp2 + lane-local l accumulation + pack P (both qf, no serialization)
#pragma unroll
        for (int qf = 0; qf < 2; qf++) {
            float mref = m_i[qf];
            f32x4 sum4 = {};
#pragma unroll
            for (int t = 0; t < 2; t++) {
#pragma unroll
                for (int i = 0; i < 4; i++) s[qf][t][i] = fexp2(s[qf][t][i] - mref);
                sum4 += s[qf][t];
            }
            lsum[qf] += (sum4[0] + sum4[1]) + (sum4[2] + sum4[3]);
            char* base = pw + qf * 2048 + lr * 128;
#pragma unroll
            for (int t = 0; t < 2; t++) {
                unsigned int lo = pk2(s[qf][t][0], s[qf][t][1]);
                unsigned int hi = pk2(s[qf][t][2], s[qf][t][3]);
                int byte0 = ((t << 5) + (lg << 3)) ^ swz;
                *(unsigned int*)(base + byte0)     = lo;
                *(unsigned int*)(base + byte0 + 4) = hi;
            }
        }
        s16x8 pa0 = *(const s16x8*)(pw + lr * 128 + ((lg << 4) ^ swz));
        s16x8 pa1 = *(const s16x8*)(pw + 2048 + lr * 128 + ((lg << 4) ^ swz));
        // PV: V from LDS: lane needs V[j=lg*8+e][c=16cf+lr]
        __builtin_amdgcn_s_setprio(1);
#pragma unroll
        for (int cf = 0; cf < 8; cf++) {
            s16x8 vb = *(const s16x8*)(vbb + ((16 * cf + lr) << 6) +
                                       ((lg ^ (lr & 3)) << 4));
            oacc[0][cf] = mfma16(pa0, vb, oacc[0][cf]);
            oacc[1][cf] = mfma16(pa1, vb, oacc[1][cf]);
        }
        __builtin_amdgcn_s_setprio(0);
        __syncthreads();
        pb ^= 1;
    }
    // finalize l: 2 shuffles once per chunk
    float l_i[2];
#pragma unroll
    for (int qf = 0; qf < 2; qf++) {
        float rs = lsum[qf];
        rs += __shfl_xor(rs, 16);
        rs += __shfl_xor(rs, 32);
        l_i[qf] = rs;
    }
    // write unnormalized partial O + (m,l)
#pragma unroll
    for (int qf = 0; qf < 2; qf++) {
#pragma unroll
        for (int i = 0; i < 4; i++) {
            size_t row = ((size_t)(cz * B_ + b) * N_ + q0 + 16 * qf + lg * 4 + i) * CI_;
#pragma unroll
            for (int cf = 0; cf < 8; cf++)
                OP[row + 16 * cf + lr] = __float2bfloat16(oacc[qf][cf][i]);
        }
        if (lg == 0) {
            size_t mi = ((size_t)(cz * B_ + b) * N_ + q0 + 16 * qf + lr) * 2;
            ML[mi] = m_i[qf];
            ML[mi + 1] = l_i[qf];
        }
    }
}

// ---------------- combine split-KV partials -> O ---------------------------
template <int NC>
__global__ __launch_bounds__(256) void combine(char* ws,
                                               unsigned long long off_part,
                                               unsigned long long off_ml) {
    const __hip_bfloat16* OP = (const __hip_bfloat16*)(ws + off_part);
    const float* ML = (const float*)(ws + off_ml);
    __hip_bfloat16* O = (__hip_bfloat16*)(ws + OFF_O);
    int idx = blockIdx.x * 256 + threadIdx.x;      // B*N*16 threads
    int cg = idx & 15, n = (idx >> 4) & (N_ - 1), b = idx >> 16;
    float mz[NC], lz[NC], M = -1e30f;
#pragma unroll
    for (int z = 0; z < NC; z++) {
        size_t mi = ((size_t)(z * B_ + b) * N_ + n) * 2;
        mz[z] = ML[mi]; lz[z] = ML[mi + 1];
        M = fmaxf(M, mz[z]);
    }
    float Lsum = 0.f, wz[NC];
#pragma unroll
    for (int z = 0; z < NC; z++) { wz[z] = exp2f(mz[z] - M); Lsum += lz[z] * wz[z]; }
    float inv = 1.f / Lsum;
    float o[8] = {};
#pragma unroll
    for (int z = 0; z < NC; z++) {
        s16x8 v = ld8(OP + ((size_t)(z * B_ + b) * N_ + n) * CI_ + cg * 8);
#pragma unroll
        for (int i = 0; i < 8; i++) o[i] += wz[z] * b2f(v[i]);
    }
    s16x8 r;
#pragma unroll
    for (int i = 0; i < 8; i++) {
        __hip_bfloat16 h = __float2bfloat16(o[i] * inv);
        r[i] = *(short*)&h;
    }
    *(s16x8*)(O + ((size_t)b * N_ + n) * CI_ + cg * 8) = r;
}

// ---------------- out projection + bias + residual (single pass over O) ----
__global__ __launch_bounds__(256) void gemm_out(const float* x, char* ws, float* y) {
    const __hip_bfloat16* Ob = (const __hip_bfloat16*)(ws + OFF_O);
    const __hip_bfloat16* Wo = (const __hip_bfloat16*)(ws + OFF_WOUT);
    const float* Bout = (const float*)(ws + OFF_BOUT);
    int b = blockIdx.y;
    int w = threadIdx.x >> 6, l = threadIdx.x & 63, lr = l & 15, lg = l >> 4;
    int n0 = blockIdx.x * 64;
    f32x4 acc[4][4] = {};   // [f2 o-tile][nf]
#pragma unroll
    for (int kk = 0; kk < 4; kk++) {
        s16x8 bb[4];
#pragma unroll
        for (int nf = 0; nf < 4; nf++)
            bb[nf] = ld8(Ob + (size_t)(b * N_ + n0 + 16 * nf + lr) * CI_ + kk * 32 + lg * 8);
#pragma unroll
        for (int f2 = 0; f2 < 4; f2++) {
            s16x8 a = ld8(Wo + (size_t)(w * 16 + f2 * 64 + lr) * CI_ + kk * 32 + lg * 8);
#pragma unroll
            for (int nf = 0; nf < 4; nf++)
                acc[f2][nf] = mfma16(a, bb[nf], acc[f2][nf]);
        }
    }
#pragma unroll
    for (int f2 = 0; f2 < 4; f2++) {
#pragma unroll
        for (int i = 0; i < 4; i++) {
            int o = w * 16 + f2 * 64 + lg * 4 + i;
            float bias = Bout[o];
#pragma unroll
            for (int nf = 0; nf < 4; nf++) {
                int n = n0 + 16 * nf + lr;
                size_t idx = (size_t)(b * C_ + o) * N_ + n;
                y[idx] = acc[f2][nf][i] + bias + x[idx];
            }
        }
    }
}

extern "C" void kernel_launch(void* const* d_in, const int* in_sizes, int n_in,
                              void* d_out, int out_size, void* d_ws, size_t ws_size,
                              hipStream_t stream) {
    const float* x  = (const float*)d_in[0];
    const float* wg = (const float*)d_in[1];
    const float* bg = (const float*)d_in[2];
    const float* wt = (const float*)d_in[3];
    const float* bt = (const float*)d_in[4];
    const float* wp = (const float*)d_in[5];
    const float* bp = (const float*)d_in[6];
    const float* wo = (const float*)d_in[7];
    const float* bo = (const float*)d_in[8];
    char* ws = (char*)d_ws;
    float* y = (float*)d_out;

    // split-KV factor: 6 fills 256 CUs at 3 blocks/CU exactly (768 blocks)
    unsigned long long need6 = OFF_END + (24ull << 20) + (1ull << 20);
    unsigned long long need4 = OFF_END + (16ull << 20) + (1ull << 20);
    int nchunk;
    unsigned long long off_part, off_ml;
    if (ws_size >= need6) {
        nchunk = 6; off_part = OFF_END; off_ml = OFF_END + (24ull << 20);
    } else if (ws_size >= need4) {
        nchunk = 4; off_part = OFF_END; off_ml = OFF_END + (16ull << 20);
    } else {
        nchunk = 2; off_part = OFF_XT; off_ml = OFF_END;
    }

    prep_weights<<<256, 256, 0, stream>>>(wg, bg, wt, bt, wp, bp, wo, bo, ws);
    transpose_x<<<dim3(128, 8, 4), 256, 0, stream>>>(x, ws);
    proj<<<dim3(128, 4), 256, 0, stream>>>(ws);
    flash6<<<dim3(32 * B_ * nchunk), 256, 0, stream>>>(ws, nchunk, off_part, off_ml);
    if (nchunk == 6)      combine<6><<<1024, 256, 0, stream>>>(ws, off_part, off_ml);
    else if (nchunk == 4) combine<4><<<1024, 256, 0, stream>>>(ws, off_part, off_ml);
    else                  combine<2><<<1024, 256, 0, stream>>>(ws, off_part, off_ml);
    gemm_out<<<dim3(64, 4), 256, 0, stream>>>(x, ws, y);
}